// Round 24
// baseline (272.570 us; speedup 1.0000x reference)
//
#include <hip/hip_runtime.h>

// ---------------------------------------------------------------------------
// Hetero GraphSAGE (user<->movie). LDS-binned bucketed CSR build (passB LDS
// sort), fp8 gather tables w/ HW cvt, reduction-free row-per-group gathers,
// MFMA GEMMs (proj_movie: balanced W+X double-buffer, 36.9KB LDS),
// both projections folded, z packed into xu8 padding bytes.
// ---------------------------------------------------------------------------

constexpr int NU = 100000;   // users
constexpr int NM = 50000;    // movies
constexpr int NE = 4000000;  // edges
constexpr int FU = 24;       // user feat
constexpr int FM = 404;      // movie feat
constexpr int HD = 64;       // hidden

constexpr int BSH = 8;                       // bucket = 256 node ids
constexpr int MBK = (NM + 255) >> BSH;       // 196 movie buckets
constexpr int UBK = (NU + 255) >> BSH;       // 391 user buckets
constexpr int NBK = MBK + UBK;               // 587
constexpr int EPB = 8192;                    // edges per passA block (1024 thr x 8)
constexpr int CAPE = 28672;                  // passB LDS sortbuf capacity (112 KB)

static inline size_t alignup(size_t x) { return (x + 255) & ~size_t(255); }

__device__ __forceinline__ float bf2f(unsigned short h) {
  return __uint_as_float(((unsigned int)h) << 16);
}
__device__ __forceinline__ unsigned short f2bf(float f) {
  unsigned int u = __float_as_uint(f);
  u = (u + 0x7FFFu + ((u >> 16) & 1u)) >> 16;   // RNE
  return (unsigned short)u;
}
__device__ __forceinline__ float2 unpk(unsigned u) {
  return make_float2(__uint_as_float(u << 16), __uint_as_float(u & 0xFFFF0000u));
}
// fp8 e4m3fn software decode (low 8 bits of v)
__device__ __forceinline__ float fp8dec(unsigned v) {
  unsigned u = ((v & 0x80u) << 24) | ((v & 0x7Fu) << 20);
  return __uint_as_float(u) * 0x1p120f;
}
// fp8 e4m3fn encode, RNE, clamp to +-448
__device__ __forceinline__ unsigned char f2fp8(float f) {
  float a = fminf(fabsf(f), 448.0f);
  unsigned u = __float_as_uint(a * 0x1p-120f);
  u = u + 0x7FFFFu + ((u >> 20) & 1u);
  return (unsigned char)(((u >> 20) & 0x7Fu) | ((__float_as_uint(f) >> 24) & 0x80u));
}

typedef __attribute__((ext_vector_type(2))) float f2v;

#if __has_builtin(__builtin_amdgcn_cvt_pk_f32_fp8)
#define FP8_HW 1
#endif

__device__ __forceinline__ f2v fp8lo(unsigned w) {
#ifdef FP8_HW
  return __builtin_amdgcn_cvt_pk_f32_fp8(w, false);
#else
  f2v r; r.x = fp8dec(w); r.y = fp8dec(w >> 8); return r;
#endif
}
__device__ __forceinline__ f2v fp8hi(unsigned w) {
#ifdef FP8_HW
  return __builtin_amdgcn_cvt_pk_f32_fp8(w, true);
#else
  f2v r; r.x = fp8dec(w >> 16); r.y = fp8dec(w >> 24); return r;
#endif
}
__device__ __forceinline__ unsigned pk2bf(float x, float y) {
  return (unsigned)f2bf(x) | ((unsigned)f2bf(y) << 16);
}

using bf16x8 = __attribute__((ext_vector_type(8))) short;   // 8 bf16 = 4 VGPRs
using f32x4  = __attribute__((ext_vector_type(4))) float;   // MFMA C/D frag

// ---------------- CSR build ----------------

__global__ __launch_bounds__(256) void histB_kernel(const int* __restrict__ src,
                                                    const int* __restrict__ dst,
                                                    int* __restrict__ bh) {
  __shared__ int h[NBK];
  for (int i = threadIdx.x; i < NBK; i += 256) h[i] = 0;
  __syncthreads();
  int idx = blockIdx.x * 256 + threadIdx.x;
  int stride = gridDim.x * 256;
  for (int i = idx; i < NE; i += stride) {
    atomicAdd(&h[dst[i] >> BSH], 1);
    atomicAdd(&h[MBK + (src[i] >> BSH)], 1);
  }
  __syncthreads();
  for (int i = threadIdx.x; i < NBK; i += 256) {
    int c = h[i];
    if (c) atomicAdd(&bh[i], c);
  }
}

__global__ __launch_bounds__(1024) void scanB_kernel(const int* __restrict__ bh,
                                                     int* __restrict__ bbase_m,
                                                     int* __restrict__ bbase_u,
                                                     int* __restrict__ bcur_m,
                                                     int* __restrict__ bcur_u) {
  __shared__ int tmp[1024];
  int t = threadIdx.x;
  int vm = (t < MBK) ? bh[t] : 0;
  tmp[t] = vm;
  __syncthreads();
  for (int off = 1; off < 1024; off <<= 1) {
    int v = (t >= off) ? tmp[t - off] : 0;
    __syncthreads();
    tmp[t] += v;
    __syncthreads();
  }
  if (t < MBK) {
    int e = tmp[t] - vm;
    bbase_m[t] = e; bcur_m[t] = e;
    if (t == MBK - 1) bbase_m[MBK] = tmp[t];
  }
  __syncthreads();
  int vu = (t < UBK) ? bh[MBK + t] : 0;
  tmp[t] = vu;
  __syncthreads();
  for (int off = 1; off < 1024; off <<= 1) {
    int v = (t >= off) ? tmp[t - off] : 0;
    __syncthreads();
    tmp[t] += v;
    __syncthreads();
  }
  if (t < UBK) {
    int e = tmp[t] - vu;
    bbase_u[t] = e; bcur_u[t] = e;
    if (t == UBK - 1) bbase_u[UBK] = tmp[t];
  }
}

// Pass A with LDS binning (verified config).
__global__ __launch_bounds__(1024) void passA_kernel(
    const int* __restrict__ src, const int* __restrict__ dst,
    int* __restrict__ bcur_m, int* __restrict__ bcur_u,
    unsigned* __restrict__ stage_m, unsigned* __restrict__ stage_u) {
  __shared__ int hB[NBK];
  __shared__ int cntB[NBK];
  __shared__ int gB[NBK];
  __shared__ int tmp[1024];
  __shared__ unsigned binM[EPB];
  __shared__ unsigned binU[EPB];
  int t = threadIdx.x;
  for (int i = t; i < NBK; i += 1024) hB[i] = 0;
  __syncthreads();
  int e0 = blockIdx.x * EPB + t;
  int sv[8], dv[8], rm[8], ru[8];
#pragma unroll
  for (int k = 0; k < 8; ++k) {
    int e = e0 + k * 1024;
    if (e < NE) {
      int s = src[e], d = dst[e];
      sv[k] = s; dv[k] = d;
      rm[k] = atomicAdd(&hB[d >> BSH], 1);
      ru[k] = atomicAdd(&hB[MBK + (s >> BSH)], 1);
    } else {
      sv[k] = -1;
    }
  }
  __syncthreads();
  int cm = (t < MBK) ? hB[t] : 0;
  tmp[t] = cm;
  __syncthreads();
  for (int off = 1; off < 1024; off <<= 1) {
    int v = (t >= off) ? tmp[t - off] : 0;
    __syncthreads();
    tmp[t] += v;
    __syncthreads();
  }
  int lofsM = tmp[t] - cm;
  __syncthreads();
  int cu_ = (t < UBK) ? hB[MBK + t] : 0;
  tmp[t] = cu_;
  __syncthreads();
  for (int off = 1; off < 1024; off <<= 1) {
    int v = (t >= off) ? tmp[t - off] : 0;
    __syncthreads();
    tmp[t] += v;
    __syncthreads();
  }
  int lofsU = tmp[t] - cu_;
  __syncthreads();
  if (t < MBK) { cntB[t] = cm; hB[t] = lofsM; }
  if (t < UBK) { cntB[MBK + t] = cu_; hB[MBK + t] = lofsU; }
  __syncthreads();
#pragma unroll
  for (int k = 0; k < 8; ++k) {
    if (sv[k] >= 0) {
      int s = sv[k], d = dv[k];
      binM[hB[d >> BSH] + rm[k]] = ((unsigned)(d & 255) << 24) | (unsigned)s;
      binU[hB[MBK + (s >> BSH)] + ru[k]] = ((unsigned)(s & 255) << 24) | (unsigned)d;
    }
  }
  __syncthreads();
  for (int b = t; b < NBK; b += 1024) {
    int cc = cntB[b];
    if (cc) {
      int gb = (b < MBK) ? atomicAdd(&bcur_m[b], cc) : atomicAdd(&bcur_u[b - MBK], cc);
      gB[b] = gb - hB[b];
    }
  }
  __syncthreads();
  int wv = t >> 6, ln = t & 63;
  for (int b = wv; b < MBK; b += 16) {
    int cc = cntB[b], lo = hB[b], go = hB[b] + gB[b];
    for (int j = ln; j < cc; j += 64) stage_m[go + j] = binM[lo + j];
  }
  for (int b = wv; b < UBK; b += 16) {
    int cc = cntB[MBK + b], lo = hB[MBK + b], go = hB[MBK + b] + gB[MBK + b];
    for (int j = ln; j < cc; j += 64) stage_u[go + j] = binU[lo + j];
  }
}

// Pass B: LDS sort + coalesced copy-out (verified config).
__global__ __launch_bounds__(1024) void passB_kernel(
    const int* __restrict__ bbase_m, const int* __restrict__ bbase_u,
    const unsigned* __restrict__ stage_m, const unsigned* __restrict__ stage_u,
    int* __restrict__ csr_m, int* __restrict__ csr_u,
    int* __restrict__ rp_m, int* __restrict__ rp_u) {
  __shared__ int cnt[256];
  __shared__ int sc[256];
  extern __shared__ unsigned sbuf[];
  int b = blockIdx.x;
  const unsigned* stage; int* csr; int* rp; int idbase, ntot, bb, be;
  if (b < MBK) {
    stage = stage_m; csr = csr_m; rp = rp_m;
    idbase = b << BSH; ntot = NM;
    bb = bbase_m[b]; be = bbase_m[b + 1];
  } else {
    int c = b - MBK;
    stage = stage_u; csr = csr_u; rp = rp_u;
    idbase = c << BSH; ntot = NU;
    bb = bbase_u[c]; be = bbase_u[c + 1];
  }
  int nloc = min(256, ntot - idbase);
  int t = threadIdx.x;
  int span = be - bb;
  if (t < 256) cnt[t] = 0;
  __syncthreads();
  for (int j = bb + t; j < be; j += 1024) atomicAdd(&cnt[stage[j] >> 24], 1);
  __syncthreads();
  int c0 = (t < 256) ? cnt[t] : 0;
  if (t < 256) sc[t] = c0;
  __syncthreads();
  for (int off = 1; off < 256; off <<= 1) {
    int v = 0;
    if (t < 256 && t >= off) v = sc[t - off];
    __syncthreads();
    if (t < 256) sc[t] += v;
    __syncthreads();
  }
  if (t < nloc) {
    rp[idbase + t] = bb + sc[t] - c0;
    cnt[t] = sc[t] - c0;               // local cursor
  }
  if (t == 0 && idbase + nloc == ntot) rp[ntot] = be;
  __syncthreads();
  if (span <= CAPE) {
    for (int j = bb + t; j < be; j += 1024) {
      unsigned e = stage[j];
      int pos = atomicAdd(&cnt[e >> 24], 1);
      sbuf[pos] = e & 0xFFFFFFu;
    }
    __syncthreads();
    for (int j = t; j < span; j += 1024) csr[bb + j] = (int)sbuf[j];
  } else {
    for (int j = bb + t; j < be; j += 1024) {
      unsigned e = stage[j];
      int pos = atomicAdd(&cnt[e >> 24], 1);
      csr[bb + pos] = (int)(e & 0xFFFFFFu);
    }
  }
}

// ---------------- conversions ----------------

__global__ void convXu_kernel(const float* __restrict__ xu, unsigned char* __restrict__ xu8) {
  int i = blockIdx.x * 256 + threadIdx.x;
  if (i < NU * 32) {
    int r = i >> 5, c = i & 31;
    xu8[i] = (c < FU) ? f2fp8(xu[r * FU + c]) : 0;
  }
}

__global__ void convXu16_kernel(const float* __restrict__ xu, unsigned short* __restrict__ xb) {
  int i = blockIdx.x * 256 + threadIdx.x;
  if (i < NU * 32) {
    int r = i >> 5, c = i & 31;
    unsigned short v = 0;
    if (c < FU) v = f2bf(xu[r * FU + c]);
    else if (c == 31) v = 0x3F80;   // 1.0
    xb[i] = v;
  }
}

// W_movie fp32 [64][404] -> bf16 [64][448] zero-padded
__global__ void convW_kernel(const float* __restrict__ W, unsigned short* __restrict__ Wb) {
  int i = blockIdx.x * 256 + threadIdx.x;
  if (i < HD * 448) {
    int h = i / 448, k = i - h * 448;
    Wb[i] = (k < FM) ? f2bf(W[h * FM + k]) : 0;
  }
}

// Wum96[h][96]: k<24 = (Wl1_um @ W_user); k==31 = (Wl1_um @ b_user);
// k in 32..95 = Wr1_um; else 0 (cols 24..30 MUST be zero: a24 cols 24..26
// carry packed-z garbage).   (movie side, X = [a24|hm])
__global__ void convWum_kernel(const float* __restrict__ Wl, const float* __restrict__ Wu,
                               const float* __restrict__ bu, const float* __restrict__ Wr,
                               unsigned short* __restrict__ W96) {
  int i = blockIdx.x * 256 + threadIdx.x;
  if (i >= 64 * 96) return;
  int h = i / 96, k = i - h * 96;
  float v = 0.f;
  if (k < FU) {
    for (int j = 0; j < 64; ++j) v += Wl[h * 64 + j] * Wu[j * FU + k];
  } else if (k == 31) {
    for (int j = 0; j < 64; ++j) v += Wl[h * 64 + j] * bu[j];
  } else if (k >= 32) {
    v = Wr[h * 64 + (k - 32)];
  }
  W96[i] = f2bf(v);
}

// Wmu96[h][96]: k<64 = Wl1_mu; k in 64..87 = (Wr1_mu @ W_user)[h][k-64];
// k==95 = (Wr1_mu @ b_user)[h]; else 0.   (user side, X = [aggb|xu32])
__global__ void convWmu_kernel(const float* __restrict__ Wl, const float* __restrict__ Wr,
                               const float* __restrict__ Wu, const float* __restrict__ bu,
                               unsigned short* __restrict__ W96) {
  int i = blockIdx.x * 256 + threadIdx.x;
  if (i >= 64 * 96) return;
  int h = i / 96, k = i - h * 96;
  float v = 0.f;
  if (k < 64) {
    v = Wl[h * 64 + k];
  } else if (k < 64 + FU) {
    for (int j = 0; j < 64; ++j) v += Wr[h * 64 + j] * Wu[j * FU + (k - 64)];
  } else if (k == 95) {
    for (int j = 0; j < 64; ++j) v += Wr[h * 64 + j] * bu[j];
  }
  W96[i] = f2bf(v);
}

// Movie projection via MFMA: W and X chunks both double-buffered with
// register prefetch (36.9KB LDS -> 4 blocks/CU). Writes bf16 hm + fp8 hm8.
__global__ __launch_bounds__(256) void proj_movie_kernel(
    const float* __restrict__ xm, const unsigned short* __restrict__ Wb,
    const float* __restrict__ bm, unsigned short* __restrict__ hm,
    unsigned char* __restrict__ hm8) {
  __shared__ unsigned short Ws[2][64][72];
  __shared__ unsigned short Xs[2][64][72];
  int t = threadIdx.x;
  int lane = t & 63, wid = t >> 6;
  int row0 = blockIdx.x * 64;
  int r0 = wid * 16;

  float4 xr[4];
  uint4 wr[2];
  auto loadC = [&](int c) {
    int k0 = c * 64;
#pragma unroll
    for (int j = 0; j < 4; ++j) {
      int i = t + j * 256;
      int r = i >> 4, c4 = i & 15;
      float4 v = make_float4(0.f, 0.f, 0.f, 0.f);
      if (k0 + c4 * 4 < FM && row0 + r < NM)
        v = *(const float4*)(xm + (size_t)(row0 + r) * FM + k0 + c4 * 4);
      xr[j] = v;
    }
#pragma unroll
    for (int j = 0; j < 2; ++j) {
      int i = t + j * 256;
      int h = i >> 3, g = i & 7;
      wr[j] = *(const uint4*)(Wb + (size_t)h * 448 + k0 + g * 8);
    }
  };
  auto writeC = [&](int buf) {
#pragma unroll
    for (int j = 0; j < 4; ++j) {
      int i = t + j * 256;
      int r = i >> 4, c4 = i & 15;
      ushort4 o;
      o.x = f2bf(xr[j].x); o.y = f2bf(xr[j].y);
      o.z = f2bf(xr[j].z); o.w = f2bf(xr[j].w);
      *(ushort4*)&Xs[buf][r][c4 * 4] = o;
    }
#pragma unroll
    for (int j = 0; j < 2; ++j) {
      int i = t + j * 256;
      int h = i >> 3, g = i & 7;
      *(uint4*)&Ws[buf][h][g * 8] = wr[j];
    }
  };

  loadC(0);
  writeC(0);
  f32x4 acc[4];
#pragma unroll
  for (int nt = 0; nt < 4; ++nt) acc[nt] = (f32x4){0.f, 0.f, 0.f, 0.f};

  for (int c = 0; c < 7; ++c) {
    if (c < 6) loadC(c + 1);              // issue next chunk's global loads
    __syncthreads();                       // current buf ready
    int buf = c & 1;
#pragma unroll
    for (int kk = 0; kk < 64; kk += 32) {
      bf16x8 a = *(const bf16x8*)&Xs[buf][r0 + (lane & 15)][kk + (lane >> 4) * 8];
#pragma unroll
      for (int nt = 0; nt < 4; ++nt) {
        bf16x8 b = *(const bf16x8*)&Ws[buf][nt * 16 + (lane & 15)][kk + (lane >> 4) * 8];
        acc[nt] = __builtin_amdgcn_mfma_f32_16x16x32_bf16(a, b, acc[nt], 0, 0, 0);
      }
    }
    if (c < 6) writeC((c + 1) & 1);        // safe: writes other buffer
  }

  int col = lane & 15;
  int rbase = r0 + (lane >> 4) * 4;
#pragma unroll
  for (int nt = 0; nt < 4; ++nt) {
    float b = bm[nt * 16 + col];
#pragma unroll
    for (int j = 0; j < 4; ++j) {
      int row = row0 + rbase + j;
      if (row < NM) {
        float v = acc[nt][j] + b;
        hm[(size_t)row * HD + nt * 16 + col] = f2bf(v);
        hm8[(size_t)row * HD + nt * 16 + col] = f2fp8(v);
      }
    }
  }
}

// -------- movie-side aggregation, reduction-free: 8 rows/wave x 8 lanes ----
// Each lane owns 4 bytes of the 32B row; z rides in bytes 24..26 (lane fq=6).

__global__ __launch_bounds__(256) void agg24z_kernel(
    const unsigned char* __restrict__ xu8, const int* __restrict__ rp,
    const int* __restrict__ csr, unsigned short* __restrict__ a24,
    float* __restrict__ zagg, int n) {
  int wid = threadIdx.x >> 6, lane = threadIdx.x & 63;
  int g = lane >> 3, fq = lane & 7;     // group (row) 0..7, 4B per lane
  int row = blockIdx.x * 32 + wid * 8 + g;
  if (row >= n) return;
  int beg = rp[row], end = rp[row + 1];
  const unsigned char* tb = xu8 + fq * 4;
  f2v a01 = {0.f, 0.f}, a23 = {0.f, 0.f};
  int i = beg;
  for (; i + 4 <= end; i += 4) {
    unsigned o0 = (unsigned)csr[i] << 5;
    unsigned o1 = (unsigned)csr[i + 1] << 5;
    unsigned o2 = (unsigned)csr[i + 2] << 5;
    unsigned o3 = (unsigned)csr[i + 3] << 5;
    unsigned w0 = *(const unsigned*)(tb + o0);
    unsigned w1 = *(const unsigned*)(tb + o1);
    unsigned w2 = *(const unsigned*)(tb + o2);
    unsigned w3 = *(const unsigned*)(tb + o3);
    a01 += (fp8lo(w0) + fp8lo(w1)) + (fp8lo(w2) + fp8lo(w3));
    a23 += (fp8hi(w0) + fp8hi(w1)) + (fp8hi(w2) + fp8hi(w3));
  }
  for (; i < end; ++i) {
    unsigned w = *(const unsigned*)(tb + ((unsigned)csr[i] << 5));
    a01 += fp8lo(w);
    a23 += fp8hi(w);
  }
  float inv = 1.0f / fmaxf((float)(end - beg), 1.0f);
  uint2 o;
  o.x = pk2bf(a01.x * inv, a01.y * inv);
  o.y = pk2bf(a23.x * inv, a23.y * inv);
  if (fq == 7)
    o.y = (o.y & 0xFFFFu) | ((end > beg ? 0x3F80u : 0u) << 16);   // col31 flag
  if (fq == 6)   // bytes 24..27 = z0,z1,z2,0
    *(float4*)(zagg + (size_t)row * 4) =
        make_float4(a01.x * inv, a01.y * inv, a23.x * inv, 0.f);
  *(uint2*)(a24 + (size_t)row * 32 + fq * 4) = o;
}

// ---- user-side aggregation, reduction-free: 8 rows/wave x 8 lanes (8B) ----

__global__ __launch_bounds__(256) void aggU_kernel(
    const unsigned char* __restrict__ tab8, const int* __restrict__ rp,
    const int* __restrict__ csr, unsigned short* __restrict__ out, int n) {
  int wid = threadIdx.x >> 6, lane = threadIdx.x & 63;
  int g = lane >> 3, fq = lane & 7;     // group (row) 0..7, 8B per lane
  int row = blockIdx.x * 32 + wid * 8 + g;
  if (row >= n) return;
  int beg = rp[row], end = rp[row + 1];
  const unsigned char* tb = tab8 + fq * 8;
  f2v a01 = {0.f, 0.f}, a23 = {0.f, 0.f}, a45 = {0.f, 0.f}, a67 = {0.f, 0.f};
  int i = beg;
  for (; i + 4 <= end; i += 4) {
    unsigned o0 = (unsigned)csr[i] << 6;
    unsigned o1 = (unsigned)csr[i + 1] << 6;
    unsigned o2 = (unsigned)csr[i + 2] << 6;
    unsigned o3 = (unsigned)csr[i + 3] << 6;
    uint2 w0 = *(const uint2*)(tb + o0);
    uint2 w1 = *(const uint2*)(tb + o1);
    uint2 w2 = *(const uint2*)(tb + o2);
    uint2 w3 = *(const uint2*)(tb + o3);
    a01 += (fp8lo(w0.x) + fp8lo(w1.x)) + (fp8lo(w2.x) + fp8lo(w3.x));
    a23 += (fp8hi(w0.x) + fp8hi(w1.x)) + (fp8hi(w2.x) + fp8hi(w3.x));
    a45 += (fp8lo(w0.y) + fp8lo(w1.y)) + (fp8lo(w2.y) + fp8lo(w3.y));
    a67 += (fp8hi(w0.y) + fp8hi(w1.y)) + (fp8hi(w2.y) + fp8hi(w3.y));
  }
  for (; i < end; ++i) {
    uint2 w = *(const uint2*)(tb + ((unsigned)csr[i] << 6));
    a01 += fp8lo(w.x); a23 += fp8hi(w.x);
    a45 += fp8lo(w.y); a67 += fp8hi(w.y);
  }
  float inv = 1.0f / fmaxf((float)(end - beg), 1.0f);
  uint4 o;
  o.x = pk2bf(a01.x * inv, a01.y * inv);
  o.y = pk2bf(a23.x * inv, a23.y * inv);
  o.z = pk2bf(a45.x * inv, a45.y * inv);
  o.w = pk2bf(a67.x * inv, a67.y * inv);
  *(uint4*)(out + (size_t)row * HD + fq * 8) = o;
}

// ---------------- SAGE linear via MFMA, K=96 (movie, X=[a24|hm]) -----------

__global__ __launch_bounds__(256) void sage_um_kernel(
    const unsigned short* __restrict__ a24, const unsigned short* __restrict__ hm,
    const unsigned short* __restrict__ W96, const float* __restrict__ bl,
    unsigned short* __restrict__ m1, int n) {
  __shared__ unsigned short Xs[64][104];
  __shared__ unsigned short Ws[64][104];
  int t = threadIdx.x;
  int lane = t & 63, wid = t >> 6;
  int row0 = blockIdx.x * 64;
  int r0 = wid * 16;
  for (int i = t; i < 768; i += 256) {
    int h = i / 12, g = i - h * 12;
    *(uint4*)&Ws[h][g * 8] = *(const uint4*)(W96 + (size_t)h * 96 + g * 8);
  }
  for (int i = t; i < 768; i += 256) {
    int r = i / 12, g = i - r * 12;
    uint4 v = make_uint4(0u, 0u, 0u, 0u);
    if (row0 + r < n) {
      if (g < 4) v = *(const uint4*)(a24 + (size_t)(row0 + r) * 32 + g * 8);
      else       v = *(const uint4*)(hm + (size_t)(row0 + r) * HD + (g - 4) * 8);
    }
    *(uint4*)&Xs[r][g * 8] = v;
  }
  __syncthreads();
  f32x4 acc[4];
#pragma unroll
  for (int nt = 0; nt < 4; ++nt) acc[nt] = (f32x4){0.f, 0.f, 0.f, 0.f};
#pragma unroll
  for (int kk = 0; kk < 96; kk += 32) {
    bf16x8 a = *(const bf16x8*)&Xs[r0 + (lane & 15)][kk + (lane >> 4) * 8];
#pragma unroll
    for (int nt = 0; nt < 4; ++nt) {
      bf16x8 b = *(const bf16x8*)&Ws[nt * 16 + (lane & 15)][kk + (lane >> 4) * 8];
      acc[nt] = __builtin_amdgcn_mfma_f32_16x16x32_bf16(a, b, acc[nt], 0, 0, 0);
    }
  }
  int col = lane & 15;
  int rbase = r0 + (lane >> 4) * 4;
#pragma unroll
  for (int nt = 0; nt < 4; ++nt) {
    float b = bl[nt * 16 + col];
#pragma unroll
    for (int j = 0; j < 4; ++j) {
      int row = row0 + rbase + j;
      if (row < n)
        m1[(size_t)row * HD + nt * 16 + col] = f2bf(fmaxf(acc[nt][j] + b, 0.f));
    }
  }
}

// ---------------- SAGE linear via MFMA, K=96 (user, X=[aggb|xu32]) ---------

__global__ __launch_bounds__(256) void sage96u_kernel(
    const unsigned short* __restrict__ agg, const unsigned short* __restrict__ xb,
    const unsigned short* __restrict__ W96, const float* __restrict__ bl,
    unsigned short* __restrict__ u1, int n) {
  __shared__ unsigned short Xs[64][104];
  __shared__ unsigned short Ws[64][104];
  int t = threadIdx.x;
  int lane = t & 63, wid = t >> 6;
  int row0 = blockIdx.x * 64;
  int r0 = wid * 16;
  for (int i = t; i < 768; i += 256) {
    int h = i / 12, g = i - h * 12;
    *(uint4*)&Ws[h][g * 8] = *(const uint4*)(W96 + (size_t)h * 96 + g * 8);
  }
  for (int i = t; i < 768; i += 256) {
    int r = i / 12, g = i - r * 12;
    uint4 v = make_uint4(0u, 0u, 0u, 0u);
    if (row0 + r < n) {
      if (g < 8) v = *(const uint4*)(agg + (size_t)(row0 + r) * HD + g * 8);
      else       v = *(const uint4*)(xb + (size_t)(row0 + r) * 32 + (g - 8) * 8);
    }
    *(uint4*)&Xs[r][g * 8] = v;
  }
  __syncthreads();
  f32x4 acc[4];
#pragma unroll
  for (int nt = 0; nt < 4; ++nt) acc[nt] = (f32x4){0.f, 0.f, 0.f, 0.f};
#pragma unroll
  for (int kk = 0; kk < 96; kk += 32) {
    bf16x8 a = *(const bf16x8*)&Xs[r0 + (lane & 15)][kk + (lane >> 4) * 8];
#pragma unroll
    for (int nt = 0; nt < 4; ++nt) {
      bf16x8 b = *(const bf16x8*)&Ws[nt * 16 + (lane & 15)][kk + (lane >> 4) * 8];
      acc[nt] = __builtin_amdgcn_mfma_f32_16x16x32_bf16(a, b, acc[nt], 0, 0, 0);
    }
  }
  int col = lane & 15;
  int rbase = r0 + (lane >> 4) * 4;
#pragma unroll
  for (int nt = 0; nt < 4; ++nt) {
    float b = bl[nt * 16 + col];
#pragma unroll
    for (int j = 0; j < 4; ++j) {
      int row = row0 + rbase + j;
      if (row < n)
        u1[(size_t)row * HD + nt * 16 + col] = f2bf(fmaxf(acc[nt][j] + b, 0.f));
    }
  }
}

// ---------------- layer 2: z projection packed into xu8 bytes 24..26 -------

__global__ __launch_bounds__(256) void zproj_kernel(
    const unsigned short* __restrict__ u1, const float* __restrict__ Wl2,
    unsigned char* __restrict__ xu8) {
  __shared__ float W[3][64];
  int t = threadIdx.x;
  if (t < 192) W[t / 64][t & 63] = Wl2[t];
  __syncthreads();
  int wid = t >> 6, lane = t & 63;
  int g = lane >> 4, fq = lane & 15;
  int row = blockIdx.x * 16 + wid * 4 + g;
  if (row >= NU) return;
  uint2 v = *(const uint2*)(u1 + (size_t)row * HD + fq * 4);
  float2 p0 = unpk(v.x), p1 = unpk(v.y);
  int f = fq * 4;
  float z0 = p0.x * W[0][f] + p0.y * W[0][f + 1] + p1.x * W[0][f + 2] + p1.y * W[0][f + 3];
  float z1 = p0.x * W[1][f] + p0.y * W[1][f + 1] + p1.x * W[1][f + 2] + p1.y * W[1][f + 3];
  float z2 = p0.x * W[2][f] + p0.y * W[2][f + 1] + p1.x * W[2][f + 2] + p1.y * W[2][f + 3];
#pragma unroll
  for (int off = 1; off < 16; off <<= 1) {
    z0 += __shfl_xor(z0, off);
    z1 += __shfl_xor(z1, off);
    z2 += __shfl_xor(z2, off);
  }
  if (fq == 0) {
    unsigned w = (unsigned)f2fp8(z0) | ((unsigned)f2fp8(z1) << 8)
               | ((unsigned)f2fp8(z2) << 16);
    *(unsigned*)(xu8 + (size_t)row * 32 + 24) = w;
  }
}

__global__ void out2_kernel(const float* __restrict__ zagg,
                            const unsigned short* __restrict__ m1,
                            const float* __restrict__ Wr2, const float* __restrict__ bl2,
                            float* __restrict__ out, int n) {
  int wid = threadIdx.x >> 6, lane = threadIdx.x & 63;
  int row = blockIdx.x * 4 + wid;
  if (row >= n) return;
  float mm = bf2f(m1[(size_t)row * HD + lane]);
#pragma unroll
  for (int g = 0; g < 3; ++g) {
    float p = mm * Wr2[g * HD + lane];
#pragma unroll
    for (int off = 32; off > 0; off >>= 1) p += __shfl_down(p, off);
    if (lane == 0) out[row * 3 + g] = p + zagg[row * 4 + g] + bl2[g];
  }
}

// ---------------------------------------------------------------------------

extern "C" void kernel_launch(void* const* d_in, const int* in_sizes, int n_in,
                              void* d_out, int out_size, void* d_ws, size_t ws_size,
                              hipStream_t stream) {
  const float* x_user  = (const float*)d_in[0];
  const float* x_movie = (const float*)d_in[1];
  const int*   e_src   = (const int*)d_in[2];
  const int*   e_dst   = (const int*)d_in[3];
  const float* W_user  = (const float*)d_in[4];
  const float* b_user  = (const float*)d_in[5];
  const float* W_movie = (const float*)d_in[6];
  const float* b_movie = (const float*)d_in[7];
  const float* Wl1_um  = (const float*)d_in[8];
  const float* bl1_um  = (const float*)d_in[9];
  const float* Wr1_um  = (const float*)d_in[10];
  const float* Wl1_mu  = (const float*)d_in[11];
  const float* bl1_mu  = (const float*)d_in[12];
  const float* Wr1_mu  = (const float*)d_in[13];
  const float* Wl2_um  = (const float*)d_in[14];
  const float* bl2_um  = (const float*)d_in[15];
  const float* Wr2_um  = (const float*)d_in[16];
  float* outp = (float*)d_out;

  // ---- workspace carve-up ----
  char* p = (char*)d_ws;
  size_t off = 0;
  auto take = [&](size_t bytes) { void* r = p + off; off += alignup(bytes); return r; };

  int* rp_m    = (int*)take(size_t(NM + 1) * 4);
  int* rp_u    = (int*)take(size_t(NU + 1) * 4);
  int* bh      = (int*)take(size_t(NBK) * 4);
  int* bbase_m = (int*)take(size_t(MBK + 1) * 4);
  int* bbase_u = (int*)take(size_t(UBK + 1) * 4);
  int* bcur_m  = (int*)take(size_t(MBK) * 4);
  int* bcur_u  = (int*)take(size_t(UBK) * 4);
  int* csr_m   = (int*)take(size_t(NE) * 4);
  int* csr_u   = (int*)take(size_t(NE) * 4);

  // overlay: staging (build phase) aliases feature buffers (feature phase)
  size_t ov_base = off;
  unsigned* stage_m = (unsigned*)take(size_t(NE) * 4);
  unsigned* stage_u = (unsigned*)take(size_t(NE) * 4);
  size_t stage_end = off;
  off = ov_base;
  unsigned short* hm    = (unsigned short*)take(size_t(NM) * HD * 2);
  unsigned short* u1    = (unsigned short*)take(size_t(NU) * HD * 2);
  unsigned short* m1    = (unsigned short*)take(size_t(NM) * HD * 2);
  unsigned short* aggb  = (unsigned short*)take(size_t(NU) * HD * 2);
  unsigned char*  xu8   = (unsigned char*)take(size_t(NU) * 32);
  unsigned char*  hm8   = (unsigned char*)take(size_t(NM) * HD);
  unsigned short* a24   = (unsigned short*)take(size_t(NM) * 32 * 2);
  unsigned short* xub16 = (unsigned short*)take(size_t(NU) * 32 * 2);
  if (off < stage_end) off = stage_end;
  float* zagg = (float*)take(size_t(NM) * 16);
  unsigned short* Wb    = (unsigned short*)take(size_t(HD) * 448 * 2);
  unsigned short* Wum96 = (unsigned short*)take(size_t(HD) * 96 * 2);
  unsigned short* Wmu96 = (unsigned short*)take(size_t(HD) * 96 * 2);
  if (off > ws_size) return;

  const int TB = 256;

  // ---- CSR build ----
  hipMemsetAsync(bh, 0, size_t(NBK) * 4, stream);
  histB_kernel<<<512, 256, 0, stream>>>(e_src, e_dst, bh);
  scanB_kernel<<<1, 1024, 0, stream>>>(bh, bbase_m, bbase_u, bcur_m, bcur_u);
  passA_kernel<<<(NE + EPB - 1) / EPB, 1024, 0, stream>>>(e_src, e_dst, bcur_m, bcur_u,
                                                          stage_m, stage_u);
  passB_kernel<<<NBK, 1024, CAPE * 4, stream>>>(bbase_m, bbase_u, stage_m, stage_u,
                                                csr_m, csr_u, rp_m, rp_u);

  // ---- conversions + movie projection ----
  convW_kernel<<<(HD * 448 + 255) / 256, 256, 0, stream>>>(W_movie, Wb);
  convWum_kernel<<<(64 * 96 + 255) / 256, 256, 0, stream>>>(Wl1_um, W_user, b_user,
                                                            Wr1_um, Wum96);
  convWmu_kernel<<<(64 * 96 + 255) / 256, 256, 0, stream>>>(Wl1_mu, Wr1_mu, W_user,
                                                            b_user, Wmu96);
  convXu_kernel<<<(NU * 32 + 255) / 256, 256, 0, stream>>>(x_user, xu8);
  convXu16_kernel<<<(NU * 32 + 255) / 256, 256, 0, stream>>>(x_user, xub16);
  proj_movie_kernel<<<(NM + 63) / 64, TB, 0, stream>>>(x_movie, Wb, b_movie, hm, hm8);

  // ---- user side first (z written into xu8 before movie aggregation) ------
  aggU_kernel<<<(NU + 31) / 32, TB, 0, stream>>>(hm8, rp_u, csr_u, aggb, NU);
  sage96u_kernel<<<(NU + 63) / 64, TB, 0, stream>>>(aggb, xub16, Wmu96, bl1_mu, u1, NU);
  zproj_kernel<<<(NU + 15) / 16, TB, 0, stream>>>(u1, Wl2_um, xu8);

  // ---- movie side: one gather pass serves features AND z ------------------
  agg24z_kernel<<<(NM + 31) / 32, TB, 0, stream>>>(xu8, rp_m, csr_m, a24, zagg, NM);
  sage_um_kernel<<<(NM + 63) / 64, TB, 0, stream>>>(a24, hm, Wum96, bl1_um, m1, NM);

  // ---- output ----
  out2_kernel<<<(NM + 3) / 4, TB, 0, stream>>>(zagg, m1, Wr2_um, bl2_um, outp, NM);
}

// Round 25
// 261.108 us; speedup vs baseline: 1.0439x; 1.0439x over previous
//
#include <hip/hip_runtime.h>

// ---------------------------------------------------------------------------
// Hetero GraphSAGE (user<->movie). LDS-binned bucketed CSR build (passB LDS
// sort), fp8 gather tables w/ HW cvt, reduction-free row-per-group gathers,
// MFMA GEMMs (proj_movie: 32-row tiles -> 2x grid for occupancy),
// both projections folded, z packed into xu8 padding bytes.
// ---------------------------------------------------------------------------

constexpr int NU = 100000;   // users
constexpr int NM = 50000;    // movies
constexpr int NE = 4000000;  // edges
constexpr int FU = 24;       // user feat
constexpr int FM = 404;      // movie feat
constexpr int HD = 64;       // hidden

constexpr int BSH = 8;                       // bucket = 256 node ids
constexpr int MBK = (NM + 255) >> BSH;       // 196 movie buckets
constexpr int UBK = (NU + 255) >> BSH;       // 391 user buckets
constexpr int NBK = MBK + UBK;               // 587
constexpr int EPB = 8192;                    // edges per passA block (1024 thr x 8)
constexpr int CAPE = 28672;                  // passB LDS sortbuf capacity (112 KB)

static inline size_t alignup(size_t x) { return (x + 255) & ~size_t(255); }

__device__ __forceinline__ float bf2f(unsigned short h) {
  return __uint_as_float(((unsigned int)h) << 16);
}
__device__ __forceinline__ unsigned short f2bf(float f) {
  unsigned int u = __float_as_uint(f);
  u = (u + 0x7FFFu + ((u >> 16) & 1u)) >> 16;   // RNE
  return (unsigned short)u;
}
__device__ __forceinline__ float2 unpk(unsigned u) {
  return make_float2(__uint_as_float(u << 16), __uint_as_float(u & 0xFFFF0000u));
}
// fp8 e4m3fn software decode (low 8 bits of v)
__device__ __forceinline__ float fp8dec(unsigned v) {
  unsigned u = ((v & 0x80u) << 24) | ((v & 0x7Fu) << 20);
  return __uint_as_float(u) * 0x1p120f;
}
// fp8 e4m3fn encode, RNE, clamp to +-448
__device__ __forceinline__ unsigned char f2fp8(float f) {
  float a = fminf(fabsf(f), 448.0f);
  unsigned u = __float_as_uint(a * 0x1p-120f);
  u = u + 0x7FFFFu + ((u >> 20) & 1u);
  return (unsigned char)(((u >> 20) & 0x7Fu) | ((__float_as_uint(f) >> 24) & 0x80u));
}

typedef __attribute__((ext_vector_type(2))) float f2v;

#if __has_builtin(__builtin_amdgcn_cvt_pk_f32_fp8)
#define FP8_HW 1
#endif

__device__ __forceinline__ f2v fp8lo(unsigned w) {
#ifdef FP8_HW
  return __builtin_amdgcn_cvt_pk_f32_fp8(w, false);
#else
  f2v r; r.x = fp8dec(w); r.y = fp8dec(w >> 8); return r;
#endif
}
__device__ __forceinline__ f2v fp8hi(unsigned w) {
#ifdef FP8_HW
  return __builtin_amdgcn_cvt_pk_f32_fp8(w, true);
#else
  f2v r; r.x = fp8dec(w >> 16); r.y = fp8dec(w >> 24); return r;
#endif
}
__device__ __forceinline__ unsigned pk2bf(float x, float y) {
  return (unsigned)f2bf(x) | ((unsigned)f2bf(y) << 16);
}

using bf16x8 = __attribute__((ext_vector_type(8))) short;   // 8 bf16 = 4 VGPRs
using f32x4  = __attribute__((ext_vector_type(4))) float;   // MFMA C/D frag

// ---------------- CSR build ----------------

__global__ __launch_bounds__(256) void histB_kernel(const int* __restrict__ src,
                                                    const int* __restrict__ dst,
                                                    int* __restrict__ bh) {
  __shared__ int h[NBK];
  for (int i = threadIdx.x; i < NBK; i += 256) h[i] = 0;
  __syncthreads();
  int idx = blockIdx.x * 256 + threadIdx.x;
  int stride = gridDim.x * 256;
  for (int i = idx; i < NE; i += stride) {
    atomicAdd(&h[dst[i] >> BSH], 1);
    atomicAdd(&h[MBK + (src[i] >> BSH)], 1);
  }
  __syncthreads();
  for (int i = threadIdx.x; i < NBK; i += 256) {
    int c = h[i];
    if (c) atomicAdd(&bh[i], c);
  }
}

__global__ __launch_bounds__(1024) void scanB_kernel(const int* __restrict__ bh,
                                                     int* __restrict__ bbase_m,
                                                     int* __restrict__ bbase_u,
                                                     int* __restrict__ bcur_m,
                                                     int* __restrict__ bcur_u) {
  __shared__ int tmp[1024];
  int t = threadIdx.x;
  int vm = (t < MBK) ? bh[t] : 0;
  tmp[t] = vm;
  __syncthreads();
  for (int off = 1; off < 1024; off <<= 1) {
    int v = (t >= off) ? tmp[t - off] : 0;
    __syncthreads();
    tmp[t] += v;
    __syncthreads();
  }
  if (t < MBK) {
    int e = tmp[t] - vm;
    bbase_m[t] = e; bcur_m[t] = e;
    if (t == MBK - 1) bbase_m[MBK] = tmp[t];
  }
  __syncthreads();
  int vu = (t < UBK) ? bh[MBK + t] : 0;
  tmp[t] = vu;
  __syncthreads();
  for (int off = 1; off < 1024; off <<= 1) {
    int v = (t >= off) ? tmp[t - off] : 0;
    __syncthreads();
    tmp[t] += v;
    __syncthreads();
  }
  if (t < UBK) {
    int e = tmp[t] - vu;
    bbase_u[t] = e; bcur_u[t] = e;
    if (t == UBK - 1) bbase_u[UBK] = tmp[t];
  }
}

// Pass A with LDS binning (verified config).
__global__ __launch_bounds__(1024) void passA_kernel(
    const int* __restrict__ src, const int* __restrict__ dst,
    int* __restrict__ bcur_m, int* __restrict__ bcur_u,
    unsigned* __restrict__ stage_m, unsigned* __restrict__ stage_u) {
  __shared__ int hB[NBK];
  __shared__ int cntB[NBK];
  __shared__ int gB[NBK];
  __shared__ int tmp[1024];
  __shared__ unsigned binM[EPB];
  __shared__ unsigned binU[EPB];
  int t = threadIdx.x;
  for (int i = t; i < NBK; i += 1024) hB[i] = 0;
  __syncthreads();
  int e0 = blockIdx.x * EPB + t;
  int sv[8], dv[8], rm[8], ru[8];
#pragma unroll
  for (int k = 0; k < 8; ++k) {
    int e = e0 + k * 1024;
    if (e < NE) {
      int s = src[e], d = dst[e];
      sv[k] = s; dv[k] = d;
      rm[k] = atomicAdd(&hB[d >> BSH], 1);
      ru[k] = atomicAdd(&hB[MBK + (s >> BSH)], 1);
    } else {
      sv[k] = -1;
    }
  }
  __syncthreads();
  int cm = (t < MBK) ? hB[t] : 0;
  tmp[t] = cm;
  __syncthreads();
  for (int off = 1; off < 1024; off <<= 1) {
    int v = (t >= off) ? tmp[t - off] : 0;
    __syncthreads();
    tmp[t] += v;
    __syncthreads();
  }
  int lofsM = tmp[t] - cm;
  __syncthreads();
  int cu_ = (t < UBK) ? hB[MBK + t] : 0;
  tmp[t] = cu_;
  __syncthreads();
  for (int off = 1; off < 1024; off <<= 1) {
    int v = (t >= off) ? tmp[t - off] : 0;
    __syncthreads();
    tmp[t] += v;
    __syncthreads();
  }
  int lofsU = tmp[t] - cu_;
  __syncthreads();
  if (t < MBK) { cntB[t] = cm; hB[t] = lofsM; }
  if (t < UBK) { cntB[MBK + t] = cu_; hB[MBK + t] = lofsU; }
  __syncthreads();
#pragma unroll
  for (int k = 0; k < 8; ++k) {
    if (sv[k] >= 0) {
      int s = sv[k], d = dv[k];
      binM[hB[d >> BSH] + rm[k]] = ((unsigned)(d & 255) << 24) | (unsigned)s;
      binU[hB[MBK + (s >> BSH)] + ru[k]] = ((unsigned)(s & 255) << 24) | (unsigned)d;
    }
  }
  __syncthreads();
  for (int b = t; b < NBK; b += 1024) {
    int cc = cntB[b];
    if (cc) {
      int gb = (b < MBK) ? atomicAdd(&bcur_m[b], cc) : atomicAdd(&bcur_u[b - MBK], cc);
      gB[b] = gb - hB[b];
    }
  }
  __syncthreads();
  int wv = t >> 6, ln = t & 63;
  for (int b = wv; b < MBK; b += 16) {
    int cc = cntB[b], lo = hB[b], go = hB[b] + gB[b];
    for (int j = ln; j < cc; j += 64) stage_m[go + j] = binM[lo + j];
  }
  for (int b = wv; b < UBK; b += 16) {
    int cc = cntB[MBK + b], lo = hB[MBK + b], go = hB[MBK + b] + gB[MBK + b];
    for (int j = ln; j < cc; j += 64) stage_u[go + j] = binU[lo + j];
  }
}

// Pass B: LDS sort + coalesced copy-out (verified config).
__global__ __launch_bounds__(1024) void passB_kernel(
    const int* __restrict__ bbase_m, const int* __restrict__ bbase_u,
    const unsigned* __restrict__ stage_m, const unsigned* __restrict__ stage_u,
    int* __restrict__ csr_m, int* __restrict__ csr_u,
    int* __restrict__ rp_m, int* __restrict__ rp_u) {
  __shared__ int cnt[256];
  __shared__ int sc[256];
  extern __shared__ unsigned sbuf[];
  int b = blockIdx.x;
  const unsigned* stage; int* csr; int* rp; int idbase, ntot, bb, be;
  if (b < MBK) {
    stage = stage_m; csr = csr_m; rp = rp_m;
    idbase = b << BSH; ntot = NM;
    bb = bbase_m[b]; be = bbase_m[b + 1];
  } else {
    int c = b - MBK;
    stage = stage_u; csr = csr_u; rp = rp_u;
    idbase = c << BSH; ntot = NU;
    bb = bbase_u[c]; be = bbase_u[c + 1];
  }
  int nloc = min(256, ntot - idbase);
  int t = threadIdx.x;
  int span = be - bb;
  if (t < 256) cnt[t] = 0;
  __syncthreads();
  for (int j = bb + t; j < be; j += 1024) atomicAdd(&cnt[stage[j] >> 24], 1);
  __syncthreads();
  int c0 = (t < 256) ? cnt[t] : 0;
  if (t < 256) sc[t] = c0;
  __syncthreads();
  for (int off = 1; off < 256; off <<= 1) {
    int v = 0;
    if (t < 256 && t >= off) v = sc[t - off];
    __syncthreads();
    if (t < 256) sc[t] += v;
    __syncthreads();
  }
  if (t < nloc) {
    rp[idbase + t] = bb + sc[t] - c0;
    cnt[t] = sc[t] - c0;               // local cursor
  }
  if (t == 0 && idbase + nloc == ntot) rp[ntot] = be;
  __syncthreads();
  if (span <= CAPE) {
    for (int j = bb + t; j < be; j += 1024) {
      unsigned e = stage[j];
      int pos = atomicAdd(&cnt[e >> 24], 1);
      sbuf[pos] = e & 0xFFFFFFu;
    }
    __syncthreads();
    for (int j = t; j < span; j += 1024) csr[bb + j] = (int)sbuf[j];
  } else {
    for (int j = bb + t; j < be; j += 1024) {
      unsigned e = stage[j];
      int pos = atomicAdd(&cnt[e >> 24], 1);
      csr[bb + pos] = (int)(e & 0xFFFFFFu);
    }
  }
}

// ---------------- conversions ----------------

__global__ void convXu_kernel(const float* __restrict__ xu, unsigned char* __restrict__ xu8) {
  int i = blockIdx.x * 256 + threadIdx.x;
  if (i < NU * 32) {
    int r = i >> 5, c = i & 31;
    xu8[i] = (c < FU) ? f2fp8(xu[r * FU + c]) : 0;
  }
}

__global__ void convXu16_kernel(const float* __restrict__ xu, unsigned short* __restrict__ xb) {
  int i = blockIdx.x * 256 + threadIdx.x;
  if (i < NU * 32) {
    int r = i >> 5, c = i & 31;
    unsigned short v = 0;
    if (c < FU) v = f2bf(xu[r * FU + c]);
    else if (c == 31) v = 0x3F80;   // 1.0
    xb[i] = v;
  }
}

// W_movie fp32 [64][404] -> bf16 [64][448] zero-padded
__global__ void convW_kernel(const float* __restrict__ W, unsigned short* __restrict__ Wb) {
  int i = blockIdx.x * 256 + threadIdx.x;
  if (i < HD * 448) {
    int h = i / 448, k = i - h * 448;
    Wb[i] = (k < FM) ? f2bf(W[h * FM + k]) : 0;
  }
}

// Wum96[h][96]: k<24 = (Wl1_um @ W_user); k==31 = (Wl1_um @ b_user);
// k in 32..95 = Wr1_um; else 0 (cols 24..30 MUST be zero: a24 cols 24..26
// carry packed-z garbage).   (movie side, X = [a24|hm])
__global__ void convWum_kernel(const float* __restrict__ Wl, const float* __restrict__ Wu,
                               const float* __restrict__ bu, const float* __restrict__ Wr,
                               unsigned short* __restrict__ W96) {
  int i = blockIdx.x * 256 + threadIdx.x;
  if (i >= 64 * 96) return;
  int h = i / 96, k = i - h * 96;
  float v = 0.f;
  if (k < FU) {
    for (int j = 0; j < 64; ++j) v += Wl[h * 64 + j] * Wu[j * FU + k];
  } else if (k == 31) {
    for (int j = 0; j < 64; ++j) v += Wl[h * 64 + j] * bu[j];
  } else if (k >= 32) {
    v = Wr[h * 64 + (k - 32)];
  }
  W96[i] = f2bf(v);
}

// Wmu96[h][96]: k<64 = Wl1_mu; k in 64..87 = (Wr1_mu @ W_user)[h][k-64];
// k==95 = (Wr1_mu @ b_user)[h]; else 0.   (user side, X = [aggb|xu32])
__global__ void convWmu_kernel(const float* __restrict__ Wl, const float* __restrict__ Wr,
                               const float* __restrict__ Wu, const float* __restrict__ bu,
                               unsigned short* __restrict__ W96) {
  int i = blockIdx.x * 256 + threadIdx.x;
  if (i >= 64 * 96) return;
  int h = i / 96, k = i - h * 96;
  float v = 0.f;
  if (k < 64) {
    v = Wl[h * 64 + k];
  } else if (k < 64 + FU) {
    for (int j = 0; j < 64; ++j) v += Wr[h * 64 + j] * Wu[j * FU + (k - 64)];
  } else if (k == 95) {
    for (int j = 0; j < 64; ++j) v += Wr[h * 64 + j] * bu[j];
  }
  W96[i] = f2bf(v);
}

// Movie projection via MFMA: 32-row tiles (2x grid, ~6 blocks/CU), r22-style
// two-barrier chunk loop. Writes bf16 hm + fp8 hm8.
__global__ __launch_bounds__(256) void proj_movie_kernel(
    const float* __restrict__ xm, const unsigned short* __restrict__ Wb,
    const float* __restrict__ bm, unsigned short* __restrict__ hm,
    unsigned char* __restrict__ hm8) {
  __shared__ unsigned short Xs[32][72];
  __shared__ unsigned short Ws[64][72];
  int t = threadIdx.x;
  int lane = t & 63, wid = t >> 6;
  int row0 = blockIdx.x * 32;
  int rw = (wid & 1) * 16;       // wave's 16-row group
  int ntb = (wid >> 1) * 2;      // wave's 2 col-frag base
  f32x4 acc[2];
  acc[0] = (f32x4){0.f, 0.f, 0.f, 0.f};
  acc[1] = (f32x4){0.f, 0.f, 0.f, 0.f};

  for (int c = 0; c < 7; ++c) {
    int k0 = c * 64;
    __syncthreads();
    // stage X chunk: 32 rows x 16 float4 groups
#pragma unroll
    for (int j = 0; j < 2; ++j) {
      int i = t + j * 256;
      int r = i >> 4, c4 = i & 15;
      float4 v = make_float4(0.f, 0.f, 0.f, 0.f);
      if (k0 + c4 * 4 < FM && row0 + r < NM)
        v = *(const float4*)(xm + (size_t)(row0 + r) * FM + k0 + c4 * 4);
      ushort4 o;
      o.x = f2bf(v.x); o.y = f2bf(v.y); o.z = f2bf(v.z); o.w = f2bf(v.w);
      *(ushort4*)&Xs[r][c4 * 4] = o;
    }
    // stage W chunk: 64 cols x 8 uint4 groups (Wb is zero-padded to 448)
#pragma unroll
    for (int j = 0; j < 2; ++j) {
      int i = t + j * 256;
      int h = i >> 3, g = i & 7;
      *(uint4*)&Ws[h][g * 8] = *(const uint4*)(Wb + (size_t)h * 448 + k0 + g * 8);
    }
    __syncthreads();
#pragma unroll
    for (int kk = 0; kk < 64; kk += 32) {
      bf16x8 a = *(const bf16x8*)&Xs[rw + (lane & 15)][kk + (lane >> 4) * 8];
#pragma unroll
      for (int q = 0; q < 2; ++q) {
        int nt = ntb + q;
        bf16x8 b = *(const bf16x8*)&Ws[nt * 16 + (lane & 15)][kk + (lane >> 4) * 8];
        acc[q] = __builtin_amdgcn_mfma_f32_16x16x32_bf16(a, b, acc[q], 0, 0, 0);
      }
    }
  }

  int col = lane & 15;
  int rbase = rw + (lane >> 4) * 4;
#pragma unroll
  for (int q = 0; q < 2; ++q) {
    int nt = ntb + q;
    float b = bm[nt * 16 + col];
#pragma unroll
    for (int j = 0; j < 4; ++j) {
      int row = row0 + rbase + j;
      if (row < NM) {
        float v = acc[q][j] + b;
        hm[(size_t)row * HD + nt * 16 + col] = f2bf(v);
        hm8[(size_t)row * HD + nt * 16 + col] = f2fp8(v);
      }
    }
  }
}

// -------- movie-side aggregation, reduction-free: 8 rows/wave x 8 lanes ----
// Each lane owns 4 bytes of the 32B row; z rides in bytes 24..26 (lane fq=6).

__global__ __launch_bounds__(256) void agg24z_kernel(
    const unsigned char* __restrict__ xu8, const int* __restrict__ rp,
    const int* __restrict__ csr, unsigned short* __restrict__ a24,
    float* __restrict__ zagg, int n) {
  int wid = threadIdx.x >> 6, lane = threadIdx.x & 63;
  int g = lane >> 3, fq = lane & 7;     // group (row) 0..7, 4B per lane
  int row = blockIdx.x * 32 + wid * 8 + g;
  if (row >= n) return;
  int beg = rp[row], end = rp[row + 1];
  const unsigned char* tb = xu8 + fq * 4;
  f2v a01 = {0.f, 0.f}, a23 = {0.f, 0.f};
  int i = beg;
  for (; i + 4 <= end; i += 4) {
    unsigned o0 = (unsigned)csr[i] << 5;
    unsigned o1 = (unsigned)csr[i + 1] << 5;
    unsigned o2 = (unsigned)csr[i + 2] << 5;
    unsigned o3 = (unsigned)csr[i + 3] << 5;
    unsigned w0 = *(const unsigned*)(tb + o0);
    unsigned w1 = *(const unsigned*)(tb + o1);
    unsigned w2 = *(const unsigned*)(tb + o2);
    unsigned w3 = *(const unsigned*)(tb + o3);
    a01 += (fp8lo(w0) + fp8lo(w1)) + (fp8lo(w2) + fp8lo(w3));
    a23 += (fp8hi(w0) + fp8hi(w1)) + (fp8hi(w2) + fp8hi(w3));
  }
  for (; i < end; ++i) {
    unsigned w = *(const unsigned*)(tb + ((unsigned)csr[i] << 5));
    a01 += fp8lo(w);
    a23 += fp8hi(w);
  }
  float inv = 1.0f / fmaxf((float)(end - beg), 1.0f);
  uint2 o;
  o.x = pk2bf(a01.x * inv, a01.y * inv);
  o.y = pk2bf(a23.x * inv, a23.y * inv);
  if (fq == 7)
    o.y = (o.y & 0xFFFFu) | ((end > beg ? 0x3F80u : 0u) << 16);   // col31 flag
  if (fq == 6)   // bytes 24..27 = z0,z1,z2,0
    *(float4*)(zagg + (size_t)row * 4) =
        make_float4(a01.x * inv, a01.y * inv, a23.x * inv, 0.f);
  *(uint2*)(a24 + (size_t)row * 32 + fq * 4) = o;
}

// ---- user-side aggregation, reduction-free: 8 rows/wave x 8 lanes (8B) ----

__global__ __launch_bounds__(256) void aggU_kernel(
    const unsigned char* __restrict__ tab8, const int* __restrict__ rp,
    const int* __restrict__ csr, unsigned short* __restrict__ out, int n) {
  int wid = threadIdx.x >> 6, lane = threadIdx.x & 63;
  int g = lane >> 3, fq = lane & 7;     // group (row) 0..7, 8B per lane
  int row = blockIdx.x * 32 + wid * 8 + g;
  if (row >= n) return;
  int beg = rp[row], end = rp[row + 1];
  const unsigned char* tb = tab8 + fq * 8;
  f2v a01 = {0.f, 0.f}, a23 = {0.f, 0.f}, a45 = {0.f, 0.f}, a67 = {0.f, 0.f};
  int i = beg;
  for (; i + 4 <= end; i += 4) {
    unsigned o0 = (unsigned)csr[i] << 6;
    unsigned o1 = (unsigned)csr[i + 1] << 6;
    unsigned o2 = (unsigned)csr[i + 2] << 6;
    unsigned o3 = (unsigned)csr[i + 3] << 6;
    uint2 w0 = *(const uint2*)(tb + o0);
    uint2 w1 = *(const uint2*)(tb + o1);
    uint2 w2 = *(const uint2*)(tb + o2);
    uint2 w3 = *(const uint2*)(tb + o3);
    a01 += (fp8lo(w0.x) + fp8lo(w1.x)) + (fp8lo(w2.x) + fp8lo(w3.x));
    a23 += (fp8hi(w0.x) + fp8hi(w1.x)) + (fp8hi(w2.x) + fp8hi(w3.x));
    a45 += (fp8lo(w0.y) + fp8lo(w1.y)) + (fp8lo(w2.y) + fp8lo(w3.y));
    a67 += (fp8hi(w0.y) + fp8hi(w1.y)) + (fp8hi(w2.y) + fp8hi(w3.y));
  }
  for (; i < end; ++i) {
    uint2 w = *(const uint2*)(tb + ((unsigned)csr[i] << 6));
    a01 += fp8lo(w.x); a23 += fp8hi(w.x);
    a45 += fp8lo(w.y); a67 += fp8hi(w.y);
  }
  float inv = 1.0f / fmaxf((float)(end - beg), 1.0f);
  uint4 o;
  o.x = pk2bf(a01.x * inv, a01.y * inv);
  o.y = pk2bf(a23.x * inv, a23.y * inv);
  o.z = pk2bf(a45.x * inv, a45.y * inv);
  o.w = pk2bf(a67.x * inv, a67.y * inv);
  *(uint4*)(out + (size_t)row * HD + fq * 8) = o;
}

// ---------------- SAGE linear via MFMA, K=96 (movie, X=[a24|hm]) -----------

__global__ __launch_bounds__(256) void sage_um_kernel(
    const unsigned short* __restrict__ a24, const unsigned short* __restrict__ hm,
    const unsigned short* __restrict__ W96, const float* __restrict__ bl,
    unsigned short* __restrict__ m1, int n) {
  __shared__ unsigned short Xs[64][104];
  __shared__ unsigned short Ws[64][104];
  int t = threadIdx.x;
  int lane = t & 63, wid = t >> 6;
  int row0 = blockIdx.x * 64;
  int r0 = wid * 16;
  for (int i = t; i < 768; i += 256) {
    int h = i / 12, g = i - h * 12;
    *(uint4*)&Ws[h][g * 8] = *(const uint4*)(W96 + (size_t)h * 96 + g * 8);
  }
  for (int i = t; i < 768; i += 256) {
    int r = i / 12, g = i - r * 12;
    uint4 v = make_uint4(0u, 0u, 0u, 0u);
    if (row0 + r < n) {
      if (g < 4) v = *(const uint4*)(a24 + (size_t)(row0 + r) * 32 + g * 8);
      else       v = *(const uint4*)(hm + (size_t)(row0 + r) * HD + (g - 4) * 8);
    }
    *(uint4*)&Xs[r][g * 8] = v;
  }
  __syncthreads();
  f32x4 acc[4];
#pragma unroll
  for (int nt = 0; nt < 4; ++nt) acc[nt] = (f32x4){0.f, 0.f, 0.f, 0.f};
#pragma unroll
  for (int kk = 0; kk < 96; kk += 32) {
    bf16x8 a = *(const bf16x8*)&Xs[r0 + (lane & 15)][kk + (lane >> 4) * 8];
#pragma unroll
    for (int nt = 0; nt < 4; ++nt) {
      bf16x8 b = *(const bf16x8*)&Ws[nt * 16 + (lane & 15)][kk + (lane >> 4) * 8];
      acc[nt] = __builtin_amdgcn_mfma_f32_16x16x32_bf16(a, b, acc[nt], 0, 0, 0);
    }
  }
  int col = lane & 15;
  int rbase = r0 + (lane >> 4) * 4;
#pragma unroll
  for (int nt = 0; nt < 4; ++nt) {
    float b = bl[nt * 16 + col];
#pragma unroll
    for (int j = 0; j < 4; ++j) {
      int row = row0 + rbase + j;
      if (row < n)
        m1[(size_t)row * HD + nt * 16 + col] = f2bf(fmaxf(acc[nt][j] + b, 0.f));
    }
  }
}

// ---------------- SAGE linear via MFMA, K=96 (user, X=[aggb|xu32]) ---------

__global__ __launch_bounds__(256) void sage96u_kernel(
    const unsigned short* __restrict__ agg, const unsigned short* __restrict__ xb,
    const unsigned short* __restrict__ W96, const float* __restrict__ bl,
    unsigned short* __restrict__ u1, int n) {
  __shared__ unsigned short Xs[64][104];
  __shared__ unsigned short Ws[64][104];
  int t = threadIdx.x;
  int lane = t & 63, wid = t >> 6;
  int row0 = blockIdx.x * 64;
  int r0 = wid * 16;
  for (int i = t; i < 768; i += 256) {
    int h = i / 12, g = i - h * 12;
    *(uint4*)&Ws[h][g * 8] = *(const uint4*)(W96 + (size_t)h * 96 + g * 8);
  }
  for (int i = t; i < 768; i += 256) {
    int r = i / 12, g = i - r * 12;
    uint4 v = make_uint4(0u, 0u, 0u, 0u);
    if (row0 + r < n) {
      if (g < 8) v = *(const uint4*)(agg + (size_t)(row0 + r) * HD + g * 8);
      else       v = *(const uint4*)(xb + (size_t)(row0 + r) * 32 + (g - 8) * 8);
    }
    *(uint4*)&Xs[r][g * 8] = v;
  }
  __syncthreads();
  f32x4 acc[4];
#pragma unroll
  for (int nt = 0; nt < 4; ++nt) acc[nt] = (f32x4){0.f, 0.f, 0.f, 0.f};
#pragma unroll
  for (int kk = 0; kk < 96; kk += 32) {
    bf16x8 a = *(const bf16x8*)&Xs[r0 + (lane & 15)][kk + (lane >> 4) * 8];
#pragma unroll
    for (int nt = 0; nt < 4; ++nt) {
      bf16x8 b = *(const bf16x8*)&Ws[nt * 16 + (lane & 15)][kk + (lane >> 4) * 8];
      acc[nt] = __builtin_amdgcn_mfma_f32_16x16x32_bf16(a, b, acc[nt], 0, 0, 0);
    }
  }
  int col = lane & 15;
  int rbase = r0 + (lane >> 4) * 4;
#pragma unroll
  for (int nt = 0; nt < 4; ++nt) {
    float b = bl[nt * 16 + col];
#pragma unroll
    for (int j = 0; j < 4; ++j) {
      int row = row0 + rbase + j;
      if (row < n)
        u1[(size_t)row * HD + nt * 16 + col] = f2bf(fmaxf(acc[nt][j] + b, 0.f));
    }
  }
}

// ---------------- layer 2: z projection packed into xu8 bytes 24..26 -------

__global__ __launch_bounds__(256) void zproj_kernel(
    const unsigned short* __restrict__ u1, const float* __restrict__ Wl2,
    unsigned char* __restrict__ xu8) {
  __shared__ float W[3][64];
  int t = threadIdx.x;
  if (t < 192) W[t / 64][t & 63] = Wl2[t];
  __syncthreads();
  int wid = t >> 6, lane = t & 63;
  int g = lane >> 4, fq = lane & 15;
  int row = blockIdx.x * 16 + wid * 4 + g;
  if (row >= NU) return;
  uint2 v = *(const uint2*)(u1 + (size_t)row * HD + fq * 4);
  float2 p0 = unpk(v.x), p1 = unpk(v.y);
  int f = fq * 4;
  float z0 = p0.x * W[0][f] + p0.y * W[0][f + 1] + p1.x * W[0][f + 2] + p1.y * W[0][f + 3];
  float z1 = p0.x * W[1][f] + p0.y * W[1][f + 1] + p1.x * W[1][f + 2] + p1.y * W[1][f + 3];
  float z2 = p0.x * W[2][f] + p0.y * W[2][f + 1] + p1.x * W[2][f + 2] + p1.y * W[2][f + 3];
#pragma unroll
  for (int off = 1; off < 16; off <<= 1) {
    z0 += __shfl_xor(z0, off);
    z1 += __shfl_xor(z1, off);
    z2 += __shfl_xor(z2, off);
  }
  if (fq == 0) {
    unsigned w = (unsigned)f2fp8(z0) | ((unsigned)f2fp8(z1) << 8)
               | ((unsigned)f2fp8(z2) << 16);
    *(unsigned*)(xu8 + (size_t)row * 32 + 24) = w;
  }
}

__global__ void out2_kernel(const float* __restrict__ zagg,
                            const unsigned short* __restrict__ m1,
                            const float* __restrict__ Wr2, const float* __restrict__ bl2,
                            float* __restrict__ out, int n) {
  int wid = threadIdx.x >> 6, lane = threadIdx.x & 63;
  int row = blockIdx.x * 4 + wid;
  if (row >= n) return;
  float mm = bf2f(m1[(size_t)row * HD + lane]);
#pragma unroll
  for (int g = 0; g < 3; ++g) {
    float p = mm * Wr2[g * HD + lane];
#pragma unroll
    for (int off = 32; off > 0; off >>= 1) p += __shfl_down(p, off);
    if (lane == 0) out[row * 3 + g] = p + zagg[row * 4 + g] + bl2[g];
  }
}

// ---------------------------------------------------------------------------

extern "C" void kernel_launch(void* const* d_in, const int* in_sizes, int n_in,
                              void* d_out, int out_size, void* d_ws, size_t ws_size,
                              hipStream_t stream) {
  const float* x_user  = (const float*)d_in[0];
  const float* x_movie = (const float*)d_in[1];
  const int*   e_src   = (const int*)d_in[2];
  const int*   e_dst   = (const int*)d_in[3];
  const float* W_user  = (const float*)d_in[4];
  const float* b_user  = (const float*)d_in[5];
  const float* W_movie = (const float*)d_in[6];
  const float* b_movie = (const float*)d_in[7];
  const float* Wl1_um  = (const float*)d_in[8];
  const float* bl1_um  = (const float*)d_in[9];
  const float* Wr1_um  = (const float*)d_in[10];
  const float* Wl1_mu  = (const float*)d_in[11];
  const float* bl1_mu  = (const float*)d_in[12];
  const float* Wr1_mu  = (const float*)d_in[13];
  const float* Wl2_um  = (const float*)d_in[14];
  const float* bl2_um  = (const float*)d_in[15];
  const float* Wr2_um  = (const float*)d_in[16];
  float* outp = (float*)d_out;

  // ---- workspace carve-up ----
  char* p = (char*)d_ws;
  size_t off = 0;
  auto take = [&](size_t bytes) { void* r = p + off; off += alignup(bytes); return r; };

  int* rp_m    = (int*)take(size_t(NM + 1) * 4);
  int* rp_u    = (int*)take(size_t(NU + 1) * 4);
  int* bh      = (int*)take(size_t(NBK) * 4);
  int* bbase_m = (int*)take(size_t(MBK + 1) * 4);
  int* bbase_u = (int*)take(size_t(UBK + 1) * 4);
  int* bcur_m  = (int*)take(size_t(MBK) * 4);
  int* bcur_u  = (int*)take(size_t(UBK) * 4);
  int* csr_m   = (int*)take(size_t(NE) * 4);
  int* csr_u   = (int*)take(size_t(NE) * 4);

  // overlay: staging (build phase) aliases feature buffers (feature phase)
  size_t ov_base = off;
  unsigned* stage_m = (unsigned*)take(size_t(NE) * 4);
  unsigned* stage_u = (unsigned*)take(size_t(NE) * 4);
  size_t stage_end = off;
  off = ov_base;
  unsigned short* hm    = (unsigned short*)take(size_t(NM) * HD * 2);
  unsigned short* u1    = (unsigned short*)take(size_t(NU) * HD * 2);
  unsigned short* m1    = (unsigned short*)take(size_t(NM) * HD * 2);
  unsigned short* aggb  = (unsigned short*)take(size_t(NU) * HD * 2);
  unsigned char*  xu8   = (unsigned char*)take(size_t(NU) * 32);
  unsigned char*  hm8   = (unsigned char*)take(size_t(NM) * HD);
  unsigned short* a24   = (unsigned short*)take(size_t(NM) * 32 * 2);
  unsigned short* xub16 = (unsigned short*)take(size_t(NU) * 32 * 2);
  if (off < stage_end) off = stage_end;
  float* zagg = (float*)take(size_t(NM) * 16);
  unsigned short* Wb    = (unsigned short*)take(size_t(HD) * 448 * 2);
  unsigned short* Wum96 = (unsigned short*)take(size_t(HD) * 96 * 2);
  unsigned short* Wmu96 = (unsigned short*)take(size_t(HD) * 96 * 2);
  if (off > ws_size) return;

  const int TB = 256;

  // ---- CSR build ----
  hipMemsetAsync(bh, 0, size_t(NBK) * 4, stream);
  histB_kernel<<<512, 256, 0, stream>>>(e_src, e_dst, bh);
  scanB_kernel<<<1, 1024, 0, stream>>>(bh, bbase_m, bbase_u, bcur_m, bcur_u);
  passA_kernel<<<(NE + EPB - 1) / EPB, 1024, 0, stream>>>(e_src, e_dst, bcur_m, bcur_u,
                                                          stage_m, stage_u);
  passB_kernel<<<NBK, 1024, CAPE * 4, stream>>>(bbase_m, bbase_u, stage_m, stage_u,
                                                csr_m, csr_u, rp_m, rp_u);

  // ---- conversions + movie projection ----
  convW_kernel<<<(HD * 448 + 255) / 256, 256, 0, stream>>>(W_movie, Wb);
  convWum_kernel<<<(64 * 96 + 255) / 256, 256, 0, stream>>>(Wl1_um, W_user, b_user,
                                                            Wr1_um, Wum96);
  convWmu_kernel<<<(64 * 96 + 255) / 256, 256, 0, stream>>>(Wl1_mu, Wr1_mu, W_user,
                                                            b_user, Wmu96);
  convXu_kernel<<<(NU * 32 + 255) / 256, 256, 0, stream>>>(x_user, xu8);
  convXu16_kernel<<<(NU * 32 + 255) / 256, 256, 0, stream>>>(x_user, xub16);
  proj_movie_kernel<<<(NM + 31) / 32, TB, 0, stream>>>(x_movie, Wb, b_movie, hm, hm8);

  // ---- user side first (z written into xu8 before movie aggregation) ------
  aggU_kernel<<<(NU + 31) / 32, TB, 0, stream>>>(hm8, rp_u, csr_u, aggb, NU);
  sage96u_kernel<<<(NU + 63) / 64, TB, 0, stream>>>(aggb, xub16, Wmu96, bl1_mu, u1, NU);
  zproj_kernel<<<(NU + 15) / 16, TB, 0, stream>>>(u1, Wl2_um, xu8);

  // ---- movie side: one gather pass serves features AND z ------------------
  agg24z_kernel<<<(NM + 31) / 32, TB, 0, stream>>>(xu8, rp_m, csr_m, a24, zagg, NM);
  sage_um_kernel<<<(NM + 63) / 64, TB, 0, stream>>>(a24, hm, Wum96, bl1_um, m1, NM);

  // ---- output ----
  out2_kernel<<<(NM + 3) / 4, TB, 0, stream>>>(zagg, m1, Wr2_um, bl2_um, outp, NM);
}

// Round 26
// 254.531 us; speedup vs baseline: 1.0709x; 1.0258x over previous
//
#include <hip/hip_runtime.h>

// ---------------------------------------------------------------------------
// Hetero GraphSAGE (user<->movie). LDS-binned bucketed CSR build (passB LDS
// sort), fp8 gather tables w/ HW cvt, reduction-free row-per-group gathers,
// MFMA GEMMs (16/32-row tiles for occupancy), both projections folded,
// z packed into xu8 padding bytes.
// ---------------------------------------------------------------------------

constexpr int NU = 100000;   // users
constexpr int NM = 50000;    // movies
constexpr int NE = 4000000;  // edges
constexpr int FU = 24;       // user feat
constexpr int FM = 404;      // movie feat
constexpr int HD = 64;       // hidden

constexpr int BSH = 8;                       // bucket = 256 node ids
constexpr int MBK = (NM + 255) >> BSH;       // 196 movie buckets
constexpr int UBK = (NU + 255) >> BSH;       // 391 user buckets
constexpr int NBK = MBK + UBK;               // 587
constexpr int EPB = 8192;                    // edges per passA block (1024 thr x 8)
constexpr int CAPE = 28672;                  // passB LDS sortbuf capacity (112 KB)

static inline size_t alignup(size_t x) { return (x + 255) & ~size_t(255); }

__device__ __forceinline__ float bf2f(unsigned short h) {
  return __uint_as_float(((unsigned int)h) << 16);
}
__device__ __forceinline__ unsigned short f2bf(float f) {
  unsigned int u = __float_as_uint(f);
  u = (u + 0x7FFFu + ((u >> 16) & 1u)) >> 16;   // RNE
  return (unsigned short)u;
}
__device__ __forceinline__ float2 unpk(unsigned u) {
  return make_float2(__uint_as_float(u << 16), __uint_as_float(u & 0xFFFF0000u));
}
// fp8 e4m3fn software decode (low 8 bits of v)
__device__ __forceinline__ float fp8dec(unsigned v) {
  unsigned u = ((v & 0x80u) << 24) | ((v & 0x7Fu) << 20);
  return __uint_as_float(u) * 0x1p120f;
}
// fp8 e4m3fn encode, RNE, clamp to +-448
__device__ __forceinline__ unsigned char f2fp8(float f) {
  float a = fminf(fabsf(f), 448.0f);
  unsigned u = __float_as_uint(a * 0x1p-120f);
  u = u + 0x7FFFFu + ((u >> 20) & 1u);
  return (unsigned char)(((u >> 20) & 0x7Fu) | ((__float_as_uint(f) >> 24) & 0x80u));
}

typedef __attribute__((ext_vector_type(2))) float f2v;

#if __has_builtin(__builtin_amdgcn_cvt_pk_f32_fp8)
#define FP8_HW 1
#endif

__device__ __forceinline__ f2v fp8lo(unsigned w) {
#ifdef FP8_HW
  return __builtin_amdgcn_cvt_pk_f32_fp8(w, false);
#else
  f2v r; r.x = fp8dec(w); r.y = fp8dec(w >> 8); return r;
#endif
}
__device__ __forceinline__ f2v fp8hi(unsigned w) {
#ifdef FP8_HW
  return __builtin_amdgcn_cvt_pk_f32_fp8(w, true);
#else
  f2v r; r.x = fp8dec(w >> 16); r.y = fp8dec(w >> 24); return r;
#endif
}
__device__ __forceinline__ unsigned pk2bf(float x, float y) {
  return (unsigned)f2bf(x) | ((unsigned)f2bf(y) << 16);
}

using bf16x8 = __attribute__((ext_vector_type(8))) short;   // 8 bf16 = 4 VGPRs
using f32x4  = __attribute__((ext_vector_type(4))) float;   // MFMA C/D frag

// ---------------- CSR build ----------------

__global__ __launch_bounds__(256) void histB_kernel(const int* __restrict__ src,
                                                    const int* __restrict__ dst,
                                                    int* __restrict__ bh) {
  __shared__ int h[NBK];
  for (int i = threadIdx.x; i < NBK; i += 256) h[i] = 0;
  __syncthreads();
  int idx = blockIdx.x * 256 + threadIdx.x;
  int stride = gridDim.x * 256;
  for (int i = idx; i < NE; i += stride) {
    atomicAdd(&h[dst[i] >> BSH], 1);
    atomicAdd(&h[MBK + (src[i] >> BSH)], 1);
  }
  __syncthreads();
  for (int i = threadIdx.x; i < NBK; i += 256) {
    int c = h[i];
    if (c) atomicAdd(&bh[i], c);
  }
}

__global__ __launch_bounds__(1024) void scanB_kernel(const int* __restrict__ bh,
                                                     int* __restrict__ bbase_m,
                                                     int* __restrict__ bbase_u,
                                                     int* __restrict__ bcur_m,
                                                     int* __restrict__ bcur_u) {
  __shared__ int tmp[1024];
  int t = threadIdx.x;
  int vm = (t < MBK) ? bh[t] : 0;
  tmp[t] = vm;
  __syncthreads();
  for (int off = 1; off < 1024; off <<= 1) {
    int v = (t >= off) ? tmp[t - off] : 0;
    __syncthreads();
    tmp[t] += v;
    __syncthreads();
  }
  if (t < MBK) {
    int e = tmp[t] - vm;
    bbase_m[t] = e; bcur_m[t] = e;
    if (t == MBK - 1) bbase_m[MBK] = tmp[t];
  }
  __syncthreads();
  int vu = (t < UBK) ? bh[MBK + t] : 0;
  tmp[t] = vu;
  __syncthreads();
  for (int off = 1; off < 1024; off <<= 1) {
    int v = (t >= off) ? tmp[t - off] : 0;
    __syncthreads();
    tmp[t] += v;
    __syncthreads();
  }
  if (t < UBK) {
    int e = tmp[t] - vu;
    bbase_u[t] = e; bcur_u[t] = e;
    if (t == UBK - 1) bbase_u[UBK] = tmp[t];
  }
}

// Pass A with LDS binning (verified config).
__global__ __launch_bounds__(1024) void passA_kernel(
    const int* __restrict__ src, const int* __restrict__ dst,
    int* __restrict__ bcur_m, int* __restrict__ bcur_u,
    unsigned* __restrict__ stage_m, unsigned* __restrict__ stage_u) {
  __shared__ int hB[NBK];
  __shared__ int cntB[NBK];
  __shared__ int gB[NBK];
  __shared__ int tmp[1024];
  __shared__ unsigned binM[EPB];
  __shared__ unsigned binU[EPB];
  int t = threadIdx.x;
  for (int i = t; i < NBK; i += 1024) hB[i] = 0;
  __syncthreads();
  int e0 = blockIdx.x * EPB + t;
  int sv[8], dv[8], rm[8], ru[8];
#pragma unroll
  for (int k = 0; k < 8; ++k) {
    int e = e0 + k * 1024;
    if (e < NE) {
      int s = src[e], d = dst[e];
      sv[k] = s; dv[k] = d;
      rm[k] = atomicAdd(&hB[d >> BSH], 1);
      ru[k] = atomicAdd(&hB[MBK + (s >> BSH)], 1);
    } else {
      sv[k] = -1;
    }
  }
  __syncthreads();
  int cm = (t < MBK) ? hB[t] : 0;
  tmp[t] = cm;
  __syncthreads();
  for (int off = 1; off < 1024; off <<= 1) {
    int v = (t >= off) ? tmp[t - off] : 0;
    __syncthreads();
    tmp[t] += v;
    __syncthreads();
  }
  int lofsM = tmp[t] - cm;
  __syncthreads();
  int cu_ = (t < UBK) ? hB[MBK + t] : 0;
  tmp[t] = cu_;
  __syncthreads();
  for (int off = 1; off < 1024; off <<= 1) {
    int v = (t >= off) ? tmp[t - off] : 0;
    __syncthreads();
    tmp[t] += v;
    __syncthreads();
  }
  int lofsU = tmp[t] - cu_;
  __syncthreads();
  if (t < MBK) { cntB[t] = cm; hB[t] = lofsM; }
  if (t < UBK) { cntB[MBK + t] = cu_; hB[MBK + t] = lofsU; }
  __syncthreads();
#pragma unroll
  for (int k = 0; k < 8; ++k) {
    if (sv[k] >= 0) {
      int s = sv[k], d = dv[k];
      binM[hB[d >> BSH] + rm[k]] = ((unsigned)(d & 255) << 24) | (unsigned)s;
      binU[hB[MBK + (s >> BSH)] + ru[k]] = ((unsigned)(s & 255) << 24) | (unsigned)d;
    }
  }
  __syncthreads();
  for (int b = t; b < NBK; b += 1024) {
    int cc = cntB[b];
    if (cc) {
      int gb = (b < MBK) ? atomicAdd(&bcur_m[b], cc) : atomicAdd(&bcur_u[b - MBK], cc);
      gB[b] = gb - hB[b];
    }
  }
  __syncthreads();
  int wv = t >> 6, ln = t & 63;
  for (int b = wv; b < MBK; b += 16) {
    int cc = cntB[b], lo = hB[b], go = hB[b] + gB[b];
    for (int j = ln; j < cc; j += 64) stage_m[go + j] = binM[lo + j];
  }
  for (int b = wv; b < UBK; b += 16) {
    int cc = cntB[MBK + b], lo = hB[MBK + b], go = hB[MBK + b] + gB[MBK + b];
    for (int j = ln; j < cc; j += 64) stage_u[go + j] = binU[lo + j];
  }
}

// Pass B: LDS sort + coalesced copy-out (verified config).
__global__ __launch_bounds__(1024) void passB_kernel(
    const int* __restrict__ bbase_m, const int* __restrict__ bbase_u,
    const unsigned* __restrict__ stage_m, const unsigned* __restrict__ stage_u,
    int* __restrict__ csr_m, int* __restrict__ csr_u,
    int* __restrict__ rp_m, int* __restrict__ rp_u) {
  __shared__ int cnt[256];
  __shared__ int sc[256];
  extern __shared__ unsigned sbuf[];
  int b = blockIdx.x;
  const unsigned* stage; int* csr; int* rp; int idbase, ntot, bb, be;
  if (b < MBK) {
    stage = stage_m; csr = csr_m; rp = rp_m;
    idbase = b << BSH; ntot = NM;
    bb = bbase_m[b]; be = bbase_m[b + 1];
  } else {
    int c = b - MBK;
    stage = stage_u; csr = csr_u; rp = rp_u;
    idbase = c << BSH; ntot = NU;
    bb = bbase_u[c]; be = bbase_u[c + 1];
  }
  int nloc = min(256, ntot - idbase);
  int t = threadIdx.x;
  int span = be - bb;
  if (t < 256) cnt[t] = 0;
  __syncthreads();
  for (int j = bb + t; j < be; j += 1024) atomicAdd(&cnt[stage[j] >> 24], 1);
  __syncthreads();
  int c0 = (t < 256) ? cnt[t] : 0;
  if (t < 256) sc[t] = c0;
  __syncthreads();
  for (int off = 1; off < 256; off <<= 1) {
    int v = 0;
    if (t < 256 && t >= off) v = sc[t - off];
    __syncthreads();
    if (t < 256) sc[t] += v;
    __syncthreads();
  }
  if (t < nloc) {
    rp[idbase + t] = bb + sc[t] - c0;
    cnt[t] = sc[t] - c0;               // local cursor
  }
  if (t == 0 && idbase + nloc == ntot) rp[ntot] = be;
  __syncthreads();
  if (span <= CAPE) {
    for (int j = bb + t; j < be; j += 1024) {
      unsigned e = stage[j];
      int pos = atomicAdd(&cnt[e >> 24], 1);
      sbuf[pos] = e & 0xFFFFFFu;
    }
    __syncthreads();
    for (int j = t; j < span; j += 1024) csr[bb + j] = (int)sbuf[j];
  } else {
    for (int j = bb + t; j < be; j += 1024) {
      unsigned e = stage[j];
      int pos = atomicAdd(&cnt[e >> 24], 1);
      csr[bb + pos] = (int)(e & 0xFFFFFFu);
    }
  }
}

// ---------------- conversions ----------------

// x_user fp32 [NU][24] -> fp8 [NU][32] AND bf16 [NU][32] in one pass
__global__ void convXuBoth_kernel(const float* __restrict__ xu,
                                  unsigned char* __restrict__ xu8,
                                  unsigned short* __restrict__ xb) {
  int i = blockIdx.x * 256 + threadIdx.x;
  if (i < NU * 32) {
    int r = i >> 5, c = i & 31;
    float v = (c < FU) ? xu[r * FU + c] : 0.f;
    xu8[i] = (c < FU) ? f2fp8(v) : 0;
    unsigned short b = 0;
    if (c < FU) b = f2bf(v);
    else if (c == 31) b = 0x3F80;   // 1.0 flag column
    xb[i] = b;
  }
}

// W_movie fp32 [64][404] -> bf16 [64][448] zero-padded
__global__ void convW_kernel(const float* __restrict__ W, unsigned short* __restrict__ Wb) {
  int i = blockIdx.x * 256 + threadIdx.x;
  if (i < HD * 448) {
    int h = i / 448, k = i - h * 448;
    Wb[i] = (k < FM) ? f2bf(W[h * FM + k]) : 0;
  }
}

// Wum96[h][96]: k<24 = (Wl1_um @ W_user); k==31 = (Wl1_um @ b_user);
// k in 32..95 = Wr1_um; else 0 (cols 24..30 MUST be zero: a24 cols 24..26
// carry packed-z garbage).   (movie side, X = [a24|hm])
__global__ void convWum_kernel(const float* __restrict__ Wl, const float* __restrict__ Wu,
                               const float* __restrict__ bu, const float* __restrict__ Wr,
                               unsigned short* __restrict__ W96) {
  int i = blockIdx.x * 256 + threadIdx.x;
  if (i >= 64 * 96) return;
  int h = i / 96, k = i - h * 96;
  float v = 0.f;
  if (k < FU) {
    for (int j = 0; j < 64; ++j) v += Wl[h * 64 + j] * Wu[j * FU + k];
  } else if (k == 31) {
    for (int j = 0; j < 64; ++j) v += Wl[h * 64 + j] * bu[j];
  } else if (k >= 32) {
    v = Wr[h * 64 + (k - 32)];
  }
  W96[i] = f2bf(v);
}

// Wmu96[h][96]: k<64 = Wl1_mu; k in 64..87 = (Wr1_mu @ W_user)[h][k-64];
// k==95 = (Wr1_mu @ b_user)[h]; else 0.   (user side, X = [aggb|xu32])
__global__ void convWmu_kernel(const float* __restrict__ Wl, const float* __restrict__ Wr,
                               const float* __restrict__ Wu, const float* __restrict__ bu,
                               unsigned short* __restrict__ W96) {
  int i = blockIdx.x * 256 + threadIdx.x;
  if (i >= 64 * 96) return;
  int h = i / 96, k = i - h * 96;
  float v = 0.f;
  if (k < 64) {
    v = Wl[h * 64 + k];
  } else if (k < 64 + FU) {
    for (int j = 0; j < 64; ++j) v += Wr[h * 64 + j] * Wu[j * FU + (k - 64)];
  } else if (k == 95) {
    for (int j = 0; j < 64; ++j) v += Wr[h * 64 + j] * bu[j];
  }
  W96[i] = f2bf(v);
}

// Movie projection via MFMA: 16-row tiles (grid 3125, ~12 blocks/CU).
// Each of 4 waves owns one 16-col fragment across all 16 rows.
__global__ __launch_bounds__(256) void proj_movie_kernel(
    const float* __restrict__ xm, const unsigned short* __restrict__ Wb,
    const float* __restrict__ bm, unsigned short* __restrict__ hm,
    unsigned char* __restrict__ hm8) {
  __shared__ unsigned short Xs[16][72];
  __shared__ unsigned short Ws[64][72];
  int t = threadIdx.x;
  int lane = t & 63, wid = t >> 6;
  int row0 = blockIdx.x * 16;
  f32x4 acc = (f32x4){0.f, 0.f, 0.f, 0.f};

  for (int c = 0; c < 7; ++c) {
    int k0 = c * 64;
    __syncthreads();
    // stage X chunk: 16 rows x 16 float4 groups -> 1 per thread
    {
      int r = t >> 4, c4 = t & 15;
      float4 v = make_float4(0.f, 0.f, 0.f, 0.f);
      if (k0 + c4 * 4 < FM && row0 + r < NM)
        v = *(const float4*)(xm + (size_t)(row0 + r) * FM + k0 + c4 * 4);
      ushort4 o;
      o.x = f2bf(v.x); o.y = f2bf(v.y); o.z = f2bf(v.z); o.w = f2bf(v.w);
      *(ushort4*)&Xs[r][c4 * 4] = o;
    }
    // stage W chunk: 64 cols x 8 uint4 groups -> 2 per thread
#pragma unroll
    for (int j = 0; j < 2; ++j) {
      int i = t + j * 256;
      int h = i >> 3, g = i & 7;
      *(uint4*)&Ws[h][g * 8] = *(const uint4*)(Wb + (size_t)h * 448 + k0 + g * 8);
    }
    __syncthreads();
#pragma unroll
    for (int kk = 0; kk < 64; kk += 32) {
      bf16x8 a = *(const bf16x8*)&Xs[lane & 15][kk + (lane >> 4) * 8];
      bf16x8 b = *(const bf16x8*)&Ws[wid * 16 + (lane & 15)][kk + (lane >> 4) * 8];
      acc = __builtin_amdgcn_mfma_f32_16x16x32_bf16(a, b, acc, 0, 0, 0);
    }
  }

  int col = lane & 15;
  int rbase = (lane >> 4) * 4;
  float b = bm[wid * 16 + col];
#pragma unroll
  for (int j = 0; j < 4; ++j) {
    int row = row0 + rbase + j;
    if (row < NM) {
      float v = acc[j] + b;
      hm[(size_t)row * HD + wid * 16 + col] = f2bf(v);
      hm8[(size_t)row * HD + wid * 16 + col] = f2fp8(v);
    }
  }
}

// -------- movie-side aggregation, reduction-free: 8 rows/wave x 8 lanes ----
// Each lane owns 4 bytes of the 32B row; z rides in bytes 24..26 (lane fq=6).

__global__ __launch_bounds__(256) void agg24z_kernel(
    const unsigned char* __restrict__ xu8, const int* __restrict__ rp,
    const int* __restrict__ csr, unsigned short* __restrict__ a24,
    float* __restrict__ zagg, int n) {
  int wid = threadIdx.x >> 6, lane = threadIdx.x & 63;
  int g = lane >> 3, fq = lane & 7;     // group (row) 0..7, 4B per lane
  int row = blockIdx.x * 32 + wid * 8 + g;
  if (row >= n) return;
  int beg = rp[row], end = rp[row + 1];
  const unsigned char* tb = xu8 + fq * 4;
  f2v a01 = {0.f, 0.f}, a23 = {0.f, 0.f};
  int i = beg;
  for (; i + 4 <= end; i += 4) {
    unsigned o0 = (unsigned)csr[i] << 5;
    unsigned o1 = (unsigned)csr[i + 1] << 5;
    unsigned o2 = (unsigned)csr[i + 2] << 5;
    unsigned o3 = (unsigned)csr[i + 3] << 5;
    unsigned w0 = *(const unsigned*)(tb + o0);
    unsigned w1 = *(const unsigned*)(tb + o1);
    unsigned w2 = *(const unsigned*)(tb + o2);
    unsigned w3 = *(const unsigned*)(tb + o3);
    a01 += (fp8lo(w0) + fp8lo(w1)) + (fp8lo(w2) + fp8lo(w3));
    a23 += (fp8hi(w0) + fp8hi(w1)) + (fp8hi(w2) + fp8hi(w3));
  }
  for (; i < end; ++i) {
    unsigned w = *(const unsigned*)(tb + ((unsigned)csr[i] << 5));
    a01 += fp8lo(w);
    a23 += fp8hi(w);
  }
  float inv = 1.0f / fmaxf((float)(end - beg), 1.0f);
  uint2 o;
  o.x = pk2bf(a01.x * inv, a01.y * inv);
  o.y = pk2bf(a23.x * inv, a23.y * inv);
  if (fq == 7)
    o.y = (o.y & 0xFFFFu) | ((end > beg ? 0x3F80u : 0u) << 16);   // col31 flag
  if (fq == 6)   // bytes 24..27 = z0,z1,z2,0
    *(float4*)(zagg + (size_t)row * 4) =
        make_float4(a01.x * inv, a01.y * inv, a23.x * inv, 0.f);
  *(uint2*)(a24 + (size_t)row * 32 + fq * 4) = o;
}

// ---- user-side aggregation, reduction-free: 8 rows/wave x 8 lanes (8B) ----

__global__ __launch_bounds__(256) void aggU_kernel(
    const unsigned char* __restrict__ tab8, const int* __restrict__ rp,
    const int* __restrict__ csr, unsigned short* __restrict__ out, int n) {
  int wid = threadIdx.x >> 6, lane = threadIdx.x & 63;
  int g = lane >> 3, fq = lane & 7;     // group (row) 0..7, 8B per lane
  int row = blockIdx.x * 32 + wid * 8 + g;
  if (row >= n) return;
  int beg = rp[row], end = rp[row + 1];
  const unsigned char* tb = tab8 + fq * 8;
  f2v a01 = {0.f, 0.f}, a23 = {0.f, 0.f}, a45 = {0.f, 0.f}, a67 = {0.f, 0.f};
  int i = beg;
  for (; i + 4 <= end; i += 4) {
    unsigned o0 = (unsigned)csr[i] << 6;
    unsigned o1 = (unsigned)csr[i + 1] << 6;
    unsigned o2 = (unsigned)csr[i + 2] << 6;
    unsigned o3 = (unsigned)csr[i + 3] << 6;
    uint2 w0 = *(const uint2*)(tb + o0);
    uint2 w1 = *(const uint2*)(tb + o1);
    uint2 w2 = *(const uint2*)(tb + o2);
    uint2 w3 = *(const uint2*)(tb + o3);
    a01 += (fp8lo(w0.x) + fp8lo(w1.x)) + (fp8lo(w2.x) + fp8lo(w3.x));
    a23 += (fp8hi(w0.x) + fp8hi(w1.x)) + (fp8hi(w2.x) + fp8hi(w3.x));
    a45 += (fp8lo(w0.y) + fp8lo(w1.y)) + (fp8lo(w2.y) + fp8lo(w3.y));
    a67 += (fp8hi(w0.y) + fp8hi(w1.y)) + (fp8hi(w2.y) + fp8hi(w3.y));
  }
  for (; i < end; ++i) {
    uint2 w = *(const uint2*)(tb + ((unsigned)csr[i] << 6));
    a01 += fp8lo(w.x); a23 += fp8hi(w.x);
    a45 += fp8lo(w.y); a67 += fp8hi(w.y);
  }
  float inv = 1.0f / fmaxf((float)(end - beg), 1.0f);
  uint4 o;
  o.x = pk2bf(a01.x * inv, a01.y * inv);
  o.y = pk2bf(a23.x * inv, a23.y * inv);
  o.z = pk2bf(a45.x * inv, a45.y * inv);
  o.w = pk2bf(a67.x * inv, a67.y * inv);
  *(uint4*)(out + (size_t)row * HD + fq * 8) = o;
}

// ------- SAGE linear via MFMA, K=96 (movie, X=[a24|hm]), 32-row tiles ------

__global__ __launch_bounds__(256) void sage_um_kernel(
    const unsigned short* __restrict__ a24, const unsigned short* __restrict__ hm,
    const unsigned short* __restrict__ W96, const float* __restrict__ bl,
    unsigned short* __restrict__ m1, int n) {
  __shared__ unsigned short Xs[32][104];
  __shared__ unsigned short Ws[64][104];
  int t = threadIdx.x;
  int lane = t & 63, wid = t >> 6;
  int row0 = blockIdx.x * 32;
  int rw = (wid & 1) * 16;       // wave's 16-row group
  int ntb = (wid >> 1) * 2;      // wave's 2 col-frag base
  for (int i = t; i < 768; i += 256) {
    int h = i / 12, g = i - h * 12;
    *(uint4*)&Ws[h][g * 8] = *(const uint4*)(W96 + (size_t)h * 96 + g * 8);
  }
  for (int i = t; i < 384; i += 256) {
    int r = i / 12, g = i - r * 12;
    uint4 v = make_uint4(0u, 0u, 0u, 0u);
    if (row0 + r < n) {
      if (g < 4) v = *(const uint4*)(a24 + (size_t)(row0 + r) * 32 + g * 8);
      else       v = *(const uint4*)(hm + (size_t)(row0 + r) * HD + (g - 4) * 8);
    }
    *(uint4*)&Xs[r][g * 8] = v;
  }
  __syncthreads();
  f32x4 acc[2];
  acc[0] = (f32x4){0.f, 0.f, 0.f, 0.f};
  acc[1] = (f32x4){0.f, 0.f, 0.f, 0.f};
#pragma unroll
  for (int kk = 0; kk < 96; kk += 32) {
    bf16x8 a = *(const bf16x8*)&Xs[rw + (lane & 15)][kk + (lane >> 4) * 8];
#pragma unroll
    for (int q = 0; q < 2; ++q) {
      int nt = ntb + q;
      bf16x8 b = *(const bf16x8*)&Ws[nt * 16 + (lane & 15)][kk + (lane >> 4) * 8];
      acc[q] = __builtin_amdgcn_mfma_f32_16x16x32_bf16(a, b, acc[q], 0, 0, 0);
    }
  }
  int col = lane & 15;
  int rbase = rw + (lane >> 4) * 4;
#pragma unroll
  for (int q = 0; q < 2; ++q) {
    int nt = ntb + q;
    float b = bl[nt * 16 + col];
#pragma unroll
    for (int j = 0; j < 4; ++j) {
      int row = row0 + rbase + j;
      if (row < n)
        m1[(size_t)row * HD + nt * 16 + col] = f2bf(fmaxf(acc[q][j] + b, 0.f));
    }
  }
}

// ---------------- SAGE linear via MFMA, K=96 (user, X=[aggb|xu32]) ---------

__global__ __launch_bounds__(256) void sage96u_kernel(
    const unsigned short* __restrict__ agg, const unsigned short* __restrict__ xb,
    const unsigned short* __restrict__ W96, const float* __restrict__ bl,
    unsigned short* __restrict__ u1, int n) {
  __shared__ unsigned short Xs[64][104];
  __shared__ unsigned short Ws[64][104];
  int t = threadIdx.x;
  int lane = t & 63, wid = t >> 6;
  int row0 = blockIdx.x * 64;
  int r0 = wid * 16;
  for (int i = t; i < 768; i += 256) {
    int h = i / 12, g = i - h * 12;
    *(uint4*)&Ws[h][g * 8] = *(const uint4*)(W96 + (size_t)h * 96 + g * 8);
  }
  for (int i = t; i < 768; i += 256) {
    int r = i / 12, g = i - r * 12;
    uint4 v = make_uint4(0u, 0u, 0u, 0u);
    if (row0 + r < n) {
      if (g < 8) v = *(const uint4*)(agg + (size_t)(row0 + r) * HD + g * 8);
      else       v = *(const uint4*)(xb + (size_t)(row0 + r) * 32 + (g - 8) * 8);
    }
    *(uint4*)&Xs[r][g * 8] = v;
  }
  __syncthreads();
  f32x4 acc[4];
#pragma unroll
  for (int nt = 0; nt < 4; ++nt) acc[nt] = (f32x4){0.f, 0.f, 0.f, 0.f};
#pragma unroll
  for (int kk = 0; kk < 96; kk += 32) {
    bf16x8 a = *(const bf16x8*)&Xs[r0 + (lane & 15)][kk + (lane >> 4) * 8];
#pragma unroll
    for (int nt = 0; nt < 4; ++nt) {
      bf16x8 b = *(const bf16x8*)&Ws[nt * 16 + (lane & 15)][kk + (lane >> 4) * 8];
      acc[nt] = __builtin_amdgcn_mfma_f32_16x16x32_bf16(a, b, acc[nt], 0, 0, 0);
    }
  }
  int col = lane & 15;
  int rbase = r0 + (lane >> 4) * 4;
#pragma unroll
  for (int nt = 0; nt < 4; ++nt) {
    float b = bl[nt * 16 + col];
#pragma unroll
    for (int j = 0; j < 4; ++j) {
      int row = row0 + rbase + j;
      if (row < n)
        u1[(size_t)row * HD + nt * 16 + col] = f2bf(fmaxf(acc[nt][j] + b, 0.f));
    }
  }
}

// ---------------- layer 2: z projection packed into xu8 bytes 24..26 -------

__global__ __launch_bounds__(256) void zproj_kernel(
    const unsigned short* __restrict__ u1, const float* __restrict__ Wl2,
    unsigned char* __restrict__ xu8) {
  __shared__ float W[3][64];
  int t = threadIdx.x;
  if (t < 192) W[t / 64][t & 63] = Wl2[t];
  __syncthreads();
  int wid = t >> 6, lane = t & 63;
  int g = lane >> 4, fq = lane & 15;
  int row = blockIdx.x * 16 + wid * 4 + g;
  if (row >= NU) return;
  uint2 v = *(const uint2*)(u1 + (size_t)row * HD + fq * 4);
  float2 p0 = unpk(v.x), p1 = unpk(v.y);
  int f = fq * 4;
  float z0 = p0.x * W[0][f] + p0.y * W[0][f + 1] + p1.x * W[0][f + 2] + p1.y * W[0][f + 3];
  float z1 = p0.x * W[1][f] + p0.y * W[1][f + 1] + p1.x * W[1][f + 2] + p1.y * W[1][f + 3];
  float z2 = p0.x * W[2][f] + p0.y * W[2][f + 1] + p1.x * W[2][f + 2] + p1.y * W[2][f + 3];
#pragma unroll
  for (int off = 1; off < 16; off <<= 1) {
    z0 += __shfl_xor(z0, off);
    z1 += __shfl_xor(z1, off);
    z2 += __shfl_xor(z2, off);
  }
  if (fq == 0) {
    unsigned w = (unsigned)f2fp8(z0) | ((unsigned)f2fp8(z1) << 8)
               | ((unsigned)f2fp8(z2) << 16);
    *(unsigned*)(xu8 + (size_t)row * 32 + 24) = w;
  }
}

__global__ void out2_kernel(const float* __restrict__ zagg,
                            const unsigned short* __restrict__ m1,
                            const float* __restrict__ Wr2, const float* __restrict__ bl2,
                            float* __restrict__ out, int n) {
  int wid = threadIdx.x >> 6, lane = threadIdx.x & 63;
  int row = blockIdx.x * 4 + wid;
  if (row >= n) return;
  float mm = bf2f(m1[(size_t)row * HD + lane]);
#pragma unroll
  for (int g = 0; g < 3; ++g) {
    float p = mm * Wr2[g * HD + lane];
#pragma unroll
    for (int off = 32; off > 0; off >>= 1) p += __shfl_down(p, off);
    if (lane == 0) out[row * 3 + g] = p + zagg[row * 4 + g] + bl2[g];
  }
}

// ---------------------------------------------------------------------------

extern "C" void kernel_launch(void* const* d_in, const int* in_sizes, int n_in,
                              void* d_out, int out_size, void* d_ws, size_t ws_size,
                              hipStream_t stream) {
  const float* x_user  = (const float*)d_in[0];
  const float* x_movie = (const float*)d_in[1];
  const int*   e_src   = (const int*)d_in[2];
  const int*   e_dst   = (const int*)d_in[3];
  const float* W_user  = (const float*)d_in[4];
  const float* b_user  = (const float*)d_in[5];
  const float* W_movie = (const float*)d_in[6];
  const float* b_movie = (const float*)d_in[7];
  const float* Wl1_um  = (const float*)d_in[8];
  const float* bl1_um  = (const float*)d_in[9];
  const float* Wr1_um  = (const float*)d_in[10];
  const float* Wl1_mu  = (const float*)d_in[11];
  const float* bl1_mu  = (const float*)d_in[12];
  const float* Wr1_mu  = (const float*)d_in[13];
  const float* Wl2_um  = (const float*)d_in[14];
  const float* bl2_um  = (const float*)d_in[15];
  const float* Wr2_um  = (const float*)d_in[16];
  float* outp = (float*)d_out;

  // ---- workspace carve-up ----
  char* p = (char*)d_ws;
  size_t off = 0;
  auto take = [&](size_t bytes) { void* r = p + off; off += alignup(bytes); return r; };

  int* rp_m    = (int*)take(size_t(NM + 1) * 4);
  int* rp_u    = (int*)take(size_t(NU + 1) * 4);
  int* bh      = (int*)take(size_t(NBK) * 4);
  int* bbase_m = (int*)take(size_t(MBK + 1) * 4);
  int* bbase_u = (int*)take(size_t(UBK + 1) * 4);
  int* bcur_m  = (int*)take(size_t(MBK) * 4);
  int* bcur_u  = (int*)take(size_t(UBK) * 4);
  int* csr_m   = (int*)take(size_t(NE) * 4);
  int* csr_u   = (int*)take(size_t(NE) * 4);

  // overlay: staging (build phase) aliases feature buffers (feature phase)
  size_t ov_base = off;
  unsigned* stage_m = (unsigned*)take(size_t(NE) * 4);
  unsigned* stage_u = (unsigned*)take(size_t(NE) * 4);
  size_t stage_end = off;
  off = ov_base;
  unsigned short* hm    = (unsigned short*)take(size_t(NM) * HD * 2);
  unsigned short* u1    = (unsigned short*)take(size_t(NU) * HD * 2);
  unsigned short* m1    = (unsigned short*)take(size_t(NM) * HD * 2);
  unsigned short* aggb  = (unsigned short*)take(size_t(NU) * HD * 2);
  unsigned char*  xu8   = (unsigned char*)take(size_t(NU) * 32);
  unsigned char*  hm8   = (unsigned char*)take(size_t(NM) * HD);
  unsigned short* a24   = (unsigned short*)take(size_t(NM) * 32 * 2);
  unsigned short* xub16 = (unsigned short*)take(size_t(NU) * 32 * 2);
  if (off < stage_end) off = stage_end;
  float* zagg = (float*)take(size_t(NM) * 16);
  unsigned short* Wb    = (unsigned short*)take(size_t(HD) * 448 * 2);
  unsigned short* Wum96 = (unsigned short*)take(size_t(HD) * 96 * 2);
  unsigned short* Wmu96 = (unsigned short*)take(size_t(HD) * 96 * 2);
  if (off > ws_size) return;

  const int TB = 256;

  // ---- CSR build ----
  hipMemsetAsync(bh, 0, size_t(NBK) * 4, stream);
  histB_kernel<<<512, 256, 0, stream>>>(e_src, e_dst, bh);
  scanB_kernel<<<1, 1024, 0, stream>>>(bh, bbase_m, bbase_u, bcur_m, bcur_u);
  passA_kernel<<<(NE + EPB - 1) / EPB, 1024, 0, stream>>>(e_src, e_dst, bcur_m, bcur_u,
                                                          stage_m, stage_u);
  passB_kernel<<<NBK, 1024, CAPE * 4, stream>>>(bbase_m, bbase_u, stage_m, stage_u,
                                                csr_m, csr_u, rp_m, rp_u);

  // ---- conversions + movie projection ----
  convW_kernel<<<(HD * 448 + 255) / 256, 256, 0, stream>>>(W_movie, Wb);
  convWum_kernel<<<(64 * 96 + 255) / 256, 256, 0, stream>>>(Wl1_um, W_user, b_user,
                                                            Wr1_um, Wum96);
  convWmu_kernel<<<(64 * 96 + 255) / 256, 256, 0, stream>>>(Wl1_mu, Wr1_mu, W_user,
                                                            b_user, Wmu96);
  convXuBoth_kernel<<<(NU * 32 + 255) / 256, 256, 0, stream>>>(x_user, xu8, xub16);
  proj_movie_kernel<<<(NM + 15) / 16, TB, 0, stream>>>(x_movie, Wb, b_movie, hm, hm8);

  // ---- user side first (z written into xu8 before movie aggregation) ------
  aggU_kernel<<<(NU + 31) / 32, TB, 0, stream>>>(hm8, rp_u, csr_u, aggb, NU);
  sage96u_kernel<<<(NU + 63) / 64, TB, 0, stream>>>(aggb, xub16, Wmu96, bl1_mu, u1, NU);
  zproj_kernel<<<(NU + 15) / 16, TB, 0, stream>>>(u1, Wl2_um, xu8);

  // ---- movie side: one gather pass serves features AND z ------------------
  agg24z_kernel<<<(NM + 31) / 32, TB, 0, stream>>>(xu8, rp_m, csr_m, a24, zagg, NM);
  sage_um_kernel<<<(NM + 31) / 32, TB, 0, stream>>>(a24, hm, Wum96, bl1_um, m1, NM);

  // ---- output ----
  out2_kernel<<<(NM + 3) / 4, TB, 0, stream>>>(zagg, m1, Wr2_um, bl2_um, outp, NM);
}

// Round 27
// 252.657 us; speedup vs baseline: 1.0788x; 1.0074x over previous
//
#include <hip/hip_runtime.h>

// ---------------------------------------------------------------------------
// Hetero GraphSAGE (user<->movie). LDS-binned bucketed CSR build (passB LDS
// sort), fp8 gather tables w/ HW cvt, reduction-free row-per-group gathers
// (8-deep MLP), MFMA GEMMs (16/32-row tiles), both projections folded,
// z packed into xu8 padding bytes.
// ---------------------------------------------------------------------------

constexpr int NU = 100000;   // users
constexpr int NM = 50000;    // movies
constexpr int NE = 4000000;  // edges
constexpr int FU = 24;       // user feat
constexpr int FM = 404;      // movie feat
constexpr int HD = 64;       // hidden

constexpr int BSH = 8;                       // bucket = 256 node ids
constexpr int MBK = (NM + 255) >> BSH;       // 196 movie buckets
constexpr int UBK = (NU + 255) >> BSH;       // 391 user buckets
constexpr int NBK = MBK + UBK;               // 587
constexpr int EPB = 8192;                    // edges per passA block (1024 thr x 8)
constexpr int CAPE = 28672;                  // passB LDS sortbuf capacity (112 KB)

static inline size_t alignup(size_t x) { return (x + 255) & ~size_t(255); }

__device__ __forceinline__ float bf2f(unsigned short h) {
  return __uint_as_float(((unsigned int)h) << 16);
}
__device__ __forceinline__ unsigned short f2bf(float f) {
  unsigned int u = __float_as_uint(f);
  u = (u + 0x7FFFu + ((u >> 16) & 1u)) >> 16;   // RNE
  return (unsigned short)u;
}
__device__ __forceinline__ float2 unpk(unsigned u) {
  return make_float2(__uint_as_float(u << 16), __uint_as_float(u & 0xFFFF0000u));
}
// fp8 e4m3fn software decode (low 8 bits of v)
__device__ __forceinline__ float fp8dec(unsigned v) {
  unsigned u = ((v & 0x80u) << 24) | ((v & 0x7Fu) << 20);
  return __uint_as_float(u) * 0x1p120f;
}
// fp8 e4m3fn encode, RNE, clamp to +-448
__device__ __forceinline__ unsigned char f2fp8(float f) {
  float a = fminf(fabsf(f), 448.0f);
  unsigned u = __float_as_uint(a * 0x1p-120f);
  u = u + 0x7FFFFu + ((u >> 20) & 1u);
  return (unsigned char)(((u >> 20) & 0x7Fu) | ((__float_as_uint(f) >> 24) & 0x80u));
}

typedef __attribute__((ext_vector_type(2))) float f2v;

#if __has_builtin(__builtin_amdgcn_cvt_pk_f32_fp8)
#define FP8_HW 1
#endif

__device__ __forceinline__ f2v fp8lo(unsigned w) {
#ifdef FP8_HW
  return __builtin_amdgcn_cvt_pk_f32_fp8(w, false);
#else
  f2v r; r.x = fp8dec(w); r.y = fp8dec(w >> 8); return r;
#endif
}
__device__ __forceinline__ f2v fp8hi(unsigned w) {
#ifdef FP8_HW
  return __builtin_amdgcn_cvt_pk_f32_fp8(w, true);
#else
  f2v r; r.x = fp8dec(w >> 16); r.y = fp8dec(w >> 24); return r;
#endif
}
__device__ __forceinline__ unsigned pk2bf(float x, float y) {
  return (unsigned)f2bf(x) | ((unsigned)f2bf(y) << 16);
}

using bf16x8 = __attribute__((ext_vector_type(8))) short;   // 8 bf16 = 4 VGPRs
using f32x4  = __attribute__((ext_vector_type(4))) float;   // MFMA C/D frag

// ---------------- CSR build ----------------

__global__ __launch_bounds__(256) void histB_kernel(const int* __restrict__ src,
                                                    const int* __restrict__ dst,
                                                    int* __restrict__ bh) {
  __shared__ int h[NBK];
  for (int i = threadIdx.x; i < NBK; i += 256) h[i] = 0;
  __syncthreads();
  int idx = blockIdx.x * 256 + threadIdx.x;
  int stride = gridDim.x * 256;
  for (int i = idx; i < NE; i += stride) {
    atomicAdd(&h[dst[i] >> BSH], 1);
    atomicAdd(&h[MBK + (src[i] >> BSH)], 1);
  }
  __syncthreads();
  for (int i = threadIdx.x; i < NBK; i += 256) {
    int c = h[i];
    if (c) atomicAdd(&bh[i], c);
  }
}

__global__ __launch_bounds__(1024) void scanB_kernel(const int* __restrict__ bh,
                                                     int* __restrict__ bbase_m,
                                                     int* __restrict__ bbase_u,
                                                     int* __restrict__ bcur_m,
                                                     int* __restrict__ bcur_u) {
  __shared__ int tmp[1024];
  int t = threadIdx.x;
  int vm = (t < MBK) ? bh[t] : 0;
  tmp[t] = vm;
  __syncthreads();
  for (int off = 1; off < 1024; off <<= 1) {
    int v = (t >= off) ? tmp[t - off] : 0;
    __syncthreads();
    tmp[t] += v;
    __syncthreads();
  }
  if (t < MBK) {
    int e = tmp[t] - vm;
    bbase_m[t] = e; bcur_m[t] = e;
    if (t == MBK - 1) bbase_m[MBK] = tmp[t];
  }
  __syncthreads();
  int vu = (t < UBK) ? bh[MBK + t] : 0;
  tmp[t] = vu;
  __syncthreads();
  for (int off = 1; off < 1024; off <<= 1) {
    int v = (t >= off) ? tmp[t - off] : 0;
    __syncthreads();
    tmp[t] += v;
    __syncthreads();
  }
  if (t < UBK) {
    int e = tmp[t] - vu;
    bbase_u[t] = e; bcur_u[t] = e;
    if (t == UBK - 1) bbase_u[UBK] = tmp[t];
  }
}

// Pass A with LDS binning (verified config).
__global__ __launch_bounds__(1024) void passA_kernel(
    const int* __restrict__ src, const int* __restrict__ dst,
    int* __restrict__ bcur_m, int* __restrict__ bcur_u,
    unsigned* __restrict__ stage_m, unsigned* __restrict__ stage_u) {
  __shared__ int hB[NBK];
  __shared__ int cntB[NBK];
  __shared__ int gB[NBK];
  __shared__ int tmp[1024];
  __shared__ unsigned binM[EPB];
  __shared__ unsigned binU[EPB];
  int t = threadIdx.x;
  for (int i = t; i < NBK; i += 1024) hB[i] = 0;
  __syncthreads();
  int e0 = blockIdx.x * EPB + t;
  int sv[8], dv[8], rm[8], ru[8];
#pragma unroll
  for (int k = 0; k < 8; ++k) {
    int e = e0 + k * 1024;
    if (e < NE) {
      int s = src[e], d = dst[e];
      sv[k] = s; dv[k] = d;
      rm[k] = atomicAdd(&hB[d >> BSH], 1);
      ru[k] = atomicAdd(&hB[MBK + (s >> BSH)], 1);
    } else {
      sv[k] = -1;
    }
  }
  __syncthreads();
  int cm = (t < MBK) ? hB[t] : 0;
  tmp[t] = cm;
  __syncthreads();
  for (int off = 1; off < 1024; off <<= 1) {
    int v = (t >= off) ? tmp[t - off] : 0;
    __syncthreads();
    tmp[t] += v;
    __syncthreads();
  }
  int lofsM = tmp[t] - cm;
  __syncthreads();
  int cu_ = (t < UBK) ? hB[MBK + t] : 0;
  tmp[t] = cu_;
  __syncthreads();
  for (int off = 1; off < 1024; off <<= 1) {
    int v = (t >= off) ? tmp[t - off] : 0;
    __syncthreads();
    tmp[t] += v;
    __syncthreads();
  }
  int lofsU = tmp[t] - cu_;
  __syncthreads();
  if (t < MBK) { cntB[t] = cm; hB[t] = lofsM; }
  if (t < UBK) { cntB[MBK + t] = cu_; hB[MBK + t] = lofsU; }
  __syncthreads();
#pragma unroll
  for (int k = 0; k < 8; ++k) {
    if (sv[k] >= 0) {
      int s = sv[k], d = dv[k];
      binM[hB[d >> BSH] + rm[k]] = ((unsigned)(d & 255) << 24) | (unsigned)s;
      binU[hB[MBK + (s >> BSH)] + ru[k]] = ((unsigned)(s & 255) << 24) | (unsigned)d;
    }
  }
  __syncthreads();
  for (int b = t; b < NBK; b += 1024) {
    int cc = cntB[b];
    if (cc) {
      int gb = (b < MBK) ? atomicAdd(&bcur_m[b], cc) : atomicAdd(&bcur_u[b - MBK], cc);
      gB[b] = gb - hB[b];
    }
  }
  __syncthreads();
  int wv = t >> 6, ln = t & 63;
  for (int b = wv; b < MBK; b += 16) {
    int cc = cntB[b], lo = hB[b], go = hB[b] + gB[b];
    for (int j = ln; j < cc; j += 64) stage_m[go + j] = binM[lo + j];
  }
  for (int b = wv; b < UBK; b += 16) {
    int cc = cntB[MBK + b], lo = hB[MBK + b], go = hB[MBK + b] + gB[MBK + b];
    for (int j = ln; j < cc; j += 64) stage_u[go + j] = binU[lo + j];
  }
}

// Pass B: LDS sort + coalesced copy-out (verified config).
__global__ __launch_bounds__(1024) void passB_kernel(
    const int* __restrict__ bbase_m, const int* __restrict__ bbase_u,
    const unsigned* __restrict__ stage_m, const unsigned* __restrict__ stage_u,
    int* __restrict__ csr_m, int* __restrict__ csr_u,
    int* __restrict__ rp_m, int* __restrict__ rp_u) {
  __shared__ int cnt[256];
  __shared__ int sc[256];
  extern __shared__ unsigned sbuf[];
  int b = blockIdx.x;
  const unsigned* stage; int* csr; int* rp; int idbase, ntot, bb, be;
  if (b < MBK) {
    stage = stage_m; csr = csr_m; rp = rp_m;
    idbase = b << BSH; ntot = NM;
    bb = bbase_m[b]; be = bbase_m[b + 1];
  } else {
    int c = b - MBK;
    stage = stage_u; csr = csr_u; rp = rp_u;
    idbase = c << BSH; ntot = NU;
    bb = bbase_u[c]; be = bbase_u[c + 1];
  }
  int nloc = min(256, ntot - idbase);
  int t = threadIdx.x;
  int span = be - bb;
  if (t < 256) cnt[t] = 0;
  __syncthreads();
  for (int j = bb + t; j < be; j += 1024) atomicAdd(&cnt[stage[j] >> 24], 1);
  __syncthreads();
  int c0 = (t < 256) ? cnt[t] : 0;
  if (t < 256) sc[t] = c0;
  __syncthreads();
  for (int off = 1; off < 256; off <<= 1) {
    int v = 0;
    if (t < 256 && t >= off) v = sc[t - off];
    __syncthreads();
    if (t < 256) sc[t] += v;
    __syncthreads();
  }
  if (t < nloc) {
    rp[idbase + t] = bb + sc[t] - c0;
    cnt[t] = sc[t] - c0;               // local cursor
  }
  if (t == 0 && idbase + nloc == ntot) rp[ntot] = be;
  __syncthreads();
  if (span <= CAPE) {
    for (int j = bb + t; j < be; j += 1024) {
      unsigned e = stage[j];
      int pos = atomicAdd(&cnt[e >> 24], 1);
      sbuf[pos] = e & 0xFFFFFFu;
    }
    __syncthreads();
    for (int j = t; j < span; j += 1024) csr[bb + j] = (int)sbuf[j];
  } else {
    for (int j = bb + t; j < be; j += 1024) {
      unsigned e = stage[j];
      int pos = atomicAdd(&cnt[e >> 24], 1);
      csr[bb + pos] = (int)(e & 0xFFFFFFu);
    }
  }
}

// ---------------- conversions ----------------

// x_user fp32 [NU][24] -> fp8 [NU][32] AND bf16 [NU][32] in one pass
__global__ void convXuBoth_kernel(const float* __restrict__ xu,
                                  unsigned char* __restrict__ xu8,
                                  unsigned short* __restrict__ xb) {
  int i = blockIdx.x * 256 + threadIdx.x;
  if (i < NU * 32) {
    int r = i >> 5, c = i & 31;
    float v = (c < FU) ? xu[r * FU + c] : 0.f;
    xu8[i] = (c < FU) ? f2fp8(v) : 0;
    unsigned short b = 0;
    if (c < FU) b = f2bf(v);
    else if (c == 31) b = 0x3F80;   // 1.0 flag column
    xb[i] = b;
  }
}

// W_movie fp32 [64][404] -> bf16 [64][448] zero-padded
__global__ void convW_kernel(const float* __restrict__ W, unsigned short* __restrict__ Wb) {
  int i = blockIdx.x * 256 + threadIdx.x;
  if (i < HD * 448) {
    int h = i / 448, k = i - h * 448;
    Wb[i] = (k < FM) ? f2bf(W[h * FM + k]) : 0;
  }
}

// Wum96[h][96]: k<24 = (Wl1_um @ W_user); k==31 = (Wl1_um @ b_user);
// k in 32..95 = Wr1_um; else 0 (cols 24..30 MUST be zero: a24 cols 24..26
// carry packed-z garbage).   (movie side, X = [a24|hm])
__global__ void convWum_kernel(const float* __restrict__ Wl, const float* __restrict__ Wu,
                               const float* __restrict__ bu, const float* __restrict__ Wr,
                               unsigned short* __restrict__ W96) {
  int i = blockIdx.x * 256 + threadIdx.x;
  if (i >= 64 * 96) return;
  int h = i / 96, k = i - h * 96;
  float v = 0.f;
  if (k < FU) {
    for (int j = 0; j < 64; ++j) v += Wl[h * 64 + j] * Wu[j * FU + k];
  } else if (k == 31) {
    for (int j = 0; j < 64; ++j) v += Wl[h * 64 + j] * bu[j];
  } else if (k >= 32) {
    v = Wr[h * 64 + (k - 32)];
  }
  W96[i] = f2bf(v);
}

// Wmu96[h][96]: k<64 = Wl1_mu; k in 64..87 = (Wr1_mu @ W_user)[h][k-64];
// k==95 = (Wr1_mu @ b_user)[h]; else 0.   (user side, X = [aggb|xu32])
__global__ void convWmu_kernel(const float* __restrict__ Wl, const float* __restrict__ Wr,
                               const float* __restrict__ Wu, const float* __restrict__ bu,
                               unsigned short* __restrict__ W96) {
  int i = blockIdx.x * 256 + threadIdx.x;
  if (i >= 64 * 96) return;
  int h = i / 96, k = i - h * 96;
  float v = 0.f;
  if (k < 64) {
    v = Wl[h * 64 + k];
  } else if (k < 64 + FU) {
    for (int j = 0; j < 64; ++j) v += Wr[h * 64 + j] * Wu[j * FU + (k - 64)];
  } else if (k == 95) {
    for (int j = 0; j < 64; ++j) v += Wr[h * 64 + j] * bu[j];
  }
  W96[i] = f2bf(v);
}

// Movie projection via MFMA: 16-row tiles (grid 3125, ~12 blocks/CU).
__global__ __launch_bounds__(256) void proj_movie_kernel(
    const float* __restrict__ xm, const unsigned short* __restrict__ Wb,
    const float* __restrict__ bm, unsigned short* __restrict__ hm,
    unsigned char* __restrict__ hm8) {
  __shared__ unsigned short Xs[16][72];
  __shared__ unsigned short Ws[64][72];
  int t = threadIdx.x;
  int lane = t & 63, wid = t >> 6;
  int row0 = blockIdx.x * 16;
  f32x4 acc = (f32x4){0.f, 0.f, 0.f, 0.f};

  for (int c = 0; c < 7; ++c) {
    int k0 = c * 64;
    __syncthreads();
    {
      int r = t >> 4, c4 = t & 15;
      float4 v = make_float4(0.f, 0.f, 0.f, 0.f);
      if (k0 + c4 * 4 < FM && row0 + r < NM)
        v = *(const float4*)(xm + (size_t)(row0 + r) * FM + k0 + c4 * 4);
      ushort4 o;
      o.x = f2bf(v.x); o.y = f2bf(v.y); o.z = f2bf(v.z); o.w = f2bf(v.w);
      *(ushort4*)&Xs[r][c4 * 4] = o;
    }
#pragma unroll
    for (int j = 0; j < 2; ++j) {
      int i = t + j * 256;
      int h = i >> 3, g = i & 7;
      *(uint4*)&Ws[h][g * 8] = *(const uint4*)(Wb + (size_t)h * 448 + k0 + g * 8);
    }
    __syncthreads();
#pragma unroll
    for (int kk = 0; kk < 64; kk += 32) {
      bf16x8 a = *(const bf16x8*)&Xs[lane & 15][kk + (lane >> 4) * 8];
      bf16x8 b = *(const bf16x8*)&Ws[wid * 16 + (lane & 15)][kk + (lane >> 4) * 8];
      acc = __builtin_amdgcn_mfma_f32_16x16x32_bf16(a, b, acc, 0, 0, 0);
    }
  }

  int col = lane & 15;
  int rbase = (lane >> 4) * 4;
  float b = bm[wid * 16 + col];
#pragma unroll
  for (int j = 0; j < 4; ++j) {
    int row = row0 + rbase + j;
    if (row < NM) {
      float v = acc[j] + b;
      hm[(size_t)row * HD + wid * 16 + col] = f2bf(v);
      hm8[(size_t)row * HD + wid * 16 + col] = f2fp8(v);
    }
  }
}

// -------- movie-side aggregation, reduction-free, 8-deep MLP ----------------
// 8 rows/wave x 8 lanes; lane owns 4B of the 32B row; z in bytes 24..26.

__global__ __launch_bounds__(256) void agg24z_kernel(
    const unsigned char* __restrict__ xu8, const int* __restrict__ rp,
    const int* __restrict__ csr, unsigned short* __restrict__ a24,
    float* __restrict__ zagg, int n) {
  int wid = threadIdx.x >> 6, lane = threadIdx.x & 63;
  int g = lane >> 3, fq = lane & 7;     // group (row) 0..7, 4B per lane
  int row = blockIdx.x * 32 + wid * 8 + g;
  if (row >= n) return;
  int beg = rp[row], end = rp[row + 1];
  const unsigned char* tb = xu8 + fq * 4;
  f2v a01 = {0.f, 0.f}, a23 = {0.f, 0.f};
  int i = beg;
  for (; i + 8 <= end; i += 8) {
    unsigned w0 = *(const unsigned*)(tb + ((unsigned)csr[i] << 5));
    unsigned w1 = *(const unsigned*)(tb + ((unsigned)csr[i + 1] << 5));
    unsigned w2 = *(const unsigned*)(tb + ((unsigned)csr[i + 2] << 5));
    unsigned w3 = *(const unsigned*)(tb + ((unsigned)csr[i + 3] << 5));
    unsigned w4 = *(const unsigned*)(tb + ((unsigned)csr[i + 4] << 5));
    unsigned w5 = *(const unsigned*)(tb + ((unsigned)csr[i + 5] << 5));
    unsigned w6 = *(const unsigned*)(tb + ((unsigned)csr[i + 6] << 5));
    unsigned w7 = *(const unsigned*)(tb + ((unsigned)csr[i + 7] << 5));
    a01 += (fp8lo(w0) + fp8lo(w1)) + (fp8lo(w2) + fp8lo(w3))
         + (fp8lo(w4) + fp8lo(w5)) + (fp8lo(w6) + fp8lo(w7));
    a23 += (fp8hi(w0) + fp8hi(w1)) + (fp8hi(w2) + fp8hi(w3))
         + (fp8hi(w4) + fp8hi(w5)) + (fp8hi(w6) + fp8hi(w7));
  }
  for (; i < end; ++i) {
    unsigned w = *(const unsigned*)(tb + ((unsigned)csr[i] << 5));
    a01 += fp8lo(w);
    a23 += fp8hi(w);
  }
  float inv = 1.0f / fmaxf((float)(end - beg), 1.0f);
  uint2 o;
  o.x = pk2bf(a01.x * inv, a01.y * inv);
  o.y = pk2bf(a23.x * inv, a23.y * inv);
  if (fq == 7)
    o.y = (o.y & 0xFFFFu) | ((end > beg ? 0x3F80u : 0u) << 16);   // col31 flag
  if (fq == 6)   // bytes 24..27 = z0,z1,z2,0
    *(float4*)(zagg + (size_t)row * 4) =
        make_float4(a01.x * inv, a01.y * inv, a23.x * inv, 0.f);
  *(uint2*)(a24 + (size_t)row * 32 + fq * 4) = o;
}

// ---- user-side aggregation, reduction-free, 8-deep MLP (8B lanes) ---------

__global__ __launch_bounds__(256) void aggU_kernel(
    const unsigned char* __restrict__ tab8, const int* __restrict__ rp,
    const int* __restrict__ csr, unsigned short* __restrict__ out, int n) {
  int wid = threadIdx.x >> 6, lane = threadIdx.x & 63;
  int g = lane >> 3, fq = lane & 7;     // group (row) 0..7, 8B per lane
  int row = blockIdx.x * 32 + wid * 8 + g;
  if (row >= n) return;
  int beg = rp[row], end = rp[row + 1];
  const unsigned char* tb = tab8 + fq * 8;
  f2v a01 = {0.f, 0.f}, a23 = {0.f, 0.f}, a45 = {0.f, 0.f}, a67 = {0.f, 0.f};
  int i = beg;
  for (; i + 8 <= end; i += 8) {
    uint2 w0 = *(const uint2*)(tb + ((unsigned)csr[i] << 6));
    uint2 w1 = *(const uint2*)(tb + ((unsigned)csr[i + 1] << 6));
    uint2 w2 = *(const uint2*)(tb + ((unsigned)csr[i + 2] << 6));
    uint2 w3 = *(const uint2*)(tb + ((unsigned)csr[i + 3] << 6));
    uint2 w4 = *(const uint2*)(tb + ((unsigned)csr[i + 4] << 6));
    uint2 w5 = *(const uint2*)(tb + ((unsigned)csr[i + 5] << 6));
    uint2 w6 = *(const uint2*)(tb + ((unsigned)csr[i + 6] << 6));
    uint2 w7 = *(const uint2*)(tb + ((unsigned)csr[i + 7] << 6));
    a01 += (fp8lo(w0.x) + fp8lo(w1.x)) + (fp8lo(w2.x) + fp8lo(w3.x))
         + (fp8lo(w4.x) + fp8lo(w5.x)) + (fp8lo(w6.x) + fp8lo(w7.x));
    a23 += (fp8hi(w0.x) + fp8hi(w1.x)) + (fp8hi(w2.x) + fp8hi(w3.x))
         + (fp8hi(w4.x) + fp8hi(w5.x)) + (fp8hi(w6.x) + fp8hi(w7.x));
    a45 += (fp8lo(w0.y) + fp8lo(w1.y)) + (fp8lo(w2.y) + fp8lo(w3.y))
         + (fp8lo(w4.y) + fp8lo(w5.y)) + (fp8lo(w6.y) + fp8lo(w7.y));
    a67 += (fp8hi(w0.y) + fp8hi(w1.y)) + (fp8hi(w2.y) + fp8hi(w3.y))
         + (fp8hi(w4.y) + fp8hi(w5.y)) + (fp8hi(w6.y) + fp8hi(w7.y));
  }
  for (; i < end; ++i) {
    uint2 w = *(const uint2*)(tb + ((unsigned)csr[i] << 6));
    a01 += fp8lo(w.x); a23 += fp8hi(w.x);
    a45 += fp8lo(w.y); a67 += fp8hi(w.y);
  }
  float inv = 1.0f / fmaxf((float)(end - beg), 1.0f);
  uint4 o;
  o.x = pk2bf(a01.x * inv, a01.y * inv);
  o.y = pk2bf(a23.x * inv, a23.y * inv);
  o.z = pk2bf(a45.x * inv, a45.y * inv);
  o.w = pk2bf(a67.x * inv, a67.y * inv);
  *(uint4*)(out + (size_t)row * HD + fq * 8) = o;
}

// ------- SAGE linear via MFMA, K=96 (movie, X=[a24|hm]), 32-row tiles ------

__global__ __launch_bounds__(256) void sage_um_kernel(
    const unsigned short* __restrict__ a24, const unsigned short* __restrict__ hm,
    const unsigned short* __restrict__ W96, const float* __restrict__ bl,
    unsigned short* __restrict__ m1, int n) {
  __shared__ unsigned short Xs[32][104];
  __shared__ unsigned short Ws[64][104];
  int t = threadIdx.x;
  int lane = t & 63, wid = t >> 6;
  int row0 = blockIdx.x * 32;
  int rw = (wid & 1) * 16;
  int ntb = (wid >> 1) * 2;
  for (int i = t; i < 768; i += 256) {
    int h = i / 12, g = i - h * 12;
    *(uint4*)&Ws[h][g * 8] = *(const uint4*)(W96 + (size_t)h * 96 + g * 8);
  }
  for (int i = t; i < 384; i += 256) {
    int r = i / 12, g = i - r * 12;
    uint4 v = make_uint4(0u, 0u, 0u, 0u);
    if (row0 + r < n) {
      if (g < 4) v = *(const uint4*)(a24 + (size_t)(row0 + r) * 32 + g * 8);
      else       v = *(const uint4*)(hm + (size_t)(row0 + r) * HD + (g - 4) * 8);
    }
    *(uint4*)&Xs[r][g * 8] = v;
  }
  __syncthreads();
  f32x4 acc[2];
  acc[0] = (f32x4){0.f, 0.f, 0.f, 0.f};
  acc[1] = (f32x4){0.f, 0.f, 0.f, 0.f};
#pragma unroll
  for (int kk = 0; kk < 96; kk += 32) {
    bf16x8 a = *(const bf16x8*)&Xs[rw + (lane & 15)][kk + (lane >> 4) * 8];
#pragma unroll
    for (int q = 0; q < 2; ++q) {
      int nt = ntb + q;
      bf16x8 b = *(const bf16x8*)&Ws[nt * 16 + (lane & 15)][kk + (lane >> 4) * 8];
      acc[q] = __builtin_amdgcn_mfma_f32_16x16x32_bf16(a, b, acc[q], 0, 0, 0);
    }
  }
  int col = lane & 15;
  int rbase = rw + (lane >> 4) * 4;
#pragma unroll
  for (int q = 0; q < 2; ++q) {
    int nt = ntb + q;
    float b = bl[nt * 16 + col];
#pragma unroll
    for (int j = 0; j < 4; ++j) {
      int row = row0 + rbase + j;
      if (row < n)
        m1[(size_t)row * HD + nt * 16 + col] = f2bf(fmaxf(acc[q][j] + b, 0.f));
    }
  }
}

// ---- SAGE linear via MFMA, K=96 (user, X=[aggb|xu32]), 32-row tiles -------

__global__ __launch_bounds__(256) void sage96u_kernel(
    const unsigned short* __restrict__ agg, const unsigned short* __restrict__ xb,
    const unsigned short* __restrict__ W96, const float* __restrict__ bl,
    unsigned short* __restrict__ u1, int n) {
  __shared__ unsigned short Xs[32][104];
  __shared__ unsigned short Ws[64][104];
  int t = threadIdx.x;
  int lane = t & 63, wid = t >> 6;
  int row0 = blockIdx.x * 32;
  int rw = (wid & 1) * 16;
  int ntb = (wid >> 1) * 2;
  for (int i = t; i < 768; i += 256) {
    int h = i / 12, g = i - h * 12;
    *(uint4*)&Ws[h][g * 8] = *(const uint4*)(W96 + (size_t)h * 96 + g * 8);
  }
  for (int i = t; i < 384; i += 256) {
    int r = i / 12, g = i - r * 12;
    uint4 v = make_uint4(0u, 0u, 0u, 0u);
    if (row0 + r < n) {
      if (g < 8) v = *(const uint4*)(agg + (size_t)(row0 + r) * HD + g * 8);
      else       v = *(const uint4*)(xb + (size_t)(row0 + r) * 32 + (g - 8) * 8);
    }
    *(uint4*)&Xs[r][g * 8] = v;
  }
  __syncthreads();
  f32x4 acc[2];
  acc[0] = (f32x4){0.f, 0.f, 0.f, 0.f};
  acc[1] = (f32x4){0.f, 0.f, 0.f, 0.f};
#pragma unroll
  for (int kk = 0; kk < 96; kk += 32) {
    bf16x8 a = *(const bf16x8*)&Xs[rw + (lane & 15)][kk + (lane >> 4) * 8];
#pragma unroll
    for (int q = 0; q < 2; ++q) {
      int nt = ntb + q;
      bf16x8 b = *(const bf16x8*)&Ws[nt * 16 + (lane & 15)][kk + (lane >> 4) * 8];
      acc[q] = __builtin_amdgcn_mfma_f32_16x16x32_bf16(a, b, acc[q], 0, 0, 0);
    }
  }
  int col = lane & 15;
  int rbase = rw + (lane >> 4) * 4;
#pragma unroll
  for (int q = 0; q < 2; ++q) {
    int nt = ntb + q;
    float b = bl[nt * 16 + col];
#pragma unroll
    for (int j = 0; j < 4; ++j) {
      int row = row0 + rbase + j;
      if (row < n)
        u1[(size_t)row * HD + nt * 16 + col] = f2bf(fmaxf(acc[q][j] + b, 0.f));
    }
  }
}

// ---------------- layer 2: z projection packed into xu8 bytes 24..26 -------

__global__ __launch_bounds__(256) void zproj_kernel(
    const unsigned short* __restrict__ u1, const float* __restrict__ Wl2,
    unsigned char* __restrict__ xu8) {
  __shared__ float W[3][64];
  int t = threadIdx.x;
  if (t < 192) W[t / 64][t & 63] = Wl2[t];
  __syncthreads();
  int wid = t >> 6, lane = t & 63;
  int g = lane >> 4, fq = lane & 15;
  int row = blockIdx.x * 16 + wid * 4 + g;
  if (row >= NU) return;
  uint2 v = *(const uint2*)(u1 + (size_t)row * HD + fq * 4);
  float2 p0 = unpk(v.x), p1 = unpk(v.y);
  int f = fq * 4;
  float z0 = p0.x * W[0][f] + p0.y * W[0][f + 1] + p1.x * W[0][f + 2] + p1.y * W[0][f + 3];
  float z1 = p0.x * W[1][f] + p0.y * W[1][f + 1] + p1.x * W[1][f + 2] + p1.y * W[1][f + 3];
  float z2 = p0.x * W[2][f] + p0.y * W[2][f + 1] + p1.x * W[2][f + 2] + p1.y * W[2][f + 3];
#pragma unroll
  for (int off = 1; off < 16; off <<= 1) {
    z0 += __shfl_xor(z0, off);
    z1 += __shfl_xor(z1, off);
    z2 += __shfl_xor(z2, off);
  }
  if (fq == 0) {
    unsigned w = (unsigned)f2fp8(z0) | ((unsigned)f2fp8(z1) << 8)
               | ((unsigned)f2fp8(z2) << 16);
    *(unsigned*)(xu8 + (size_t)row * 32 + 24) = w;
  }
}

__global__ void out2_kernel(const float* __restrict__ zagg,
                            const unsigned short* __restrict__ m1,
                            const float* __restrict__ Wr2, const float* __restrict__ bl2,
                            float* __restrict__ out, int n) {
  int wid = threadIdx.x >> 6, lane = threadIdx.x & 63;
  int row = blockIdx.x * 4 + wid;
  if (row >= n) return;
  float mm = bf2f(m1[(size_t)row * HD + lane]);
#pragma unroll
  for (int g = 0; g < 3; ++g) {
    float p = mm * Wr2[g * HD + lane];
#pragma unroll
    for (int off = 32; off > 0; off >>= 1) p += __shfl_down(p, off);
    if (lane == 0) out[row * 3 + g] = p + zagg[row * 4 + g] + bl2[g];
  }
}

// ---------------------------------------------------------------------------

extern "C" void kernel_launch(void* const* d_in, const int* in_sizes, int n_in,
                              void* d_out, int out_size, void* d_ws, size_t ws_size,
                              hipStream_t stream) {
  const float* x_user  = (const float*)d_in[0];
  const float* x_movie = (const float*)d_in[1];
  const int*   e_src   = (const int*)d_in[2];
  const int*   e_dst   = (const int*)d_in[3];
  const float* W_user  = (const float*)d_in[4];
  const float* b_user  = (const float*)d_in[5];
  const float* W_movie = (const float*)d_in[6];
  const float* b_movie = (const float*)d_in[7];
  const float* Wl1_um  = (const float*)d_in[8];
  const float* bl1_um  = (const float*)d_in[9];
  const float* Wr1_um  = (const float*)d_in[10];
  const float* Wl1_mu  = (const float*)d_in[11];
  const float* bl1_mu  = (const float*)d_in[12];
  const float* Wr1_mu  = (const float*)d_in[13];
  const float* Wl2_um  = (const float*)d_in[14];
  const float* bl2_um  = (const float*)d_in[15];
  const float* Wr2_um  = (const float*)d_in[16];
  float* outp = (float*)d_out;

  // ---- workspace carve-up ----
  char* p = (char*)d_ws;
  size_t off = 0;
  auto take = [&](size_t bytes) { void* r = p + off; off += alignup(bytes); return r; };

  int* rp_m    = (int*)take(size_t(NM + 1) * 4);
  int* rp_u    = (int*)take(size_t(NU + 1) * 4);
  int* bh      = (int*)take(size_t(NBK) * 4);
  int* bbase_m = (int*)take(size_t(MBK + 1) * 4);
  int* bbase_u = (int*)take(size_t(UBK + 1) * 4);
  int* bcur_m  = (int*)take(size_t(MBK) * 4);
  int* bcur_u  = (int*)take(size_t(UBK) * 4);
  int* csr_m   = (int*)take(size_t(NE) * 4);
  int* csr_u   = (int*)take(size_t(NE) * 4);

  // overlay: staging (build phase) aliases feature buffers (feature phase)
  size_t ov_base = off;
  unsigned* stage_m = (unsigned*)take(size_t(NE) * 4);
  unsigned* stage_u = (unsigned*)take(size_t(NE) * 4);
  size_t stage_end = off;
  off = ov_base;
  unsigned short* hm    = (unsigned short*)take(size_t(NM) * HD * 2);
  unsigned short* u1    = (unsigned short*)take(size_t(NU) * HD * 2);
  unsigned short* m1    = (unsigned short*)take(size_t(NM) * HD * 2);
  unsigned short* aggb  = (unsigned short*)take(size_t(NU) * HD * 2);
  unsigned char*  xu8   = (unsigned char*)take(size_t(NU) * 32);
  unsigned char*  hm8   = (unsigned char*)take(size_t(NM) * HD);
  unsigned short* a24   = (unsigned short*)take(size_t(NM) * 32 * 2);
  unsigned short* xub16 = (unsigned short*)take(size_t(NU) * 32 * 2);
  if (off < stage_end) off = stage_end;
  float* zagg = (float*)take(size_t(NM) * 16);
  unsigned short* Wb    = (unsigned short*)take(size_t(HD) * 448 * 2);
  unsigned short* Wum96 = (unsigned short*)take(size_t(HD) * 96 * 2);
  unsigned short* Wmu96 = (unsigned short*)take(size_t(HD) * 96 * 2);
  if (off > ws_size) return;

  const int TB = 256;

  // ---- CSR build ----
  hipMemsetAsync(bh, 0, size_t(NBK) * 4, stream);
  histB_kernel<<<512, 256, 0, stream>>>(e_src, e_dst, bh);
  scanB_kernel<<<1, 1024, 0, stream>>>(bh, bbase_m, bbase_u, bcur_m, bcur_u);
  passA_kernel<<<(NE + EPB - 1) / EPB, 1024, 0, stream>>>(e_src, e_dst, bcur_m, bcur_u,
                                                          stage_m, stage_u);
  passB_kernel<<<NBK, 1024, CAPE * 4, stream>>>(bbase_m, bbase_u, stage_m, stage_u,
                                                csr_m, csr_u, rp_m, rp_u);

  // ---- conversions + movie projection ----
  convW_kernel<<<(HD * 448 + 255) / 256, 256, 0, stream>>>(W_movie, Wb);
  convWum_kernel<<<(64 * 96 + 255) / 256, 256, 0, stream>>>(Wl1_um, W_user, b_user,
                                                            Wr1_um, Wum96);
  convWmu_kernel<<<(64 * 96 + 255) / 256, 256, 0, stream>>>(Wl1_mu, Wr1_mu, W_user,
                                                            b_user, Wmu96);
  convXuBoth_kernel<<<(NU * 32 + 255) / 256, 256, 0, stream>>>(x_user, xu8, xub16);
  proj_movie_kernel<<<(NM + 15) / 16, TB, 0, stream>>>(x_movie, Wb, b_movie, hm, hm8);

  // ---- user side first (z written into xu8 before movie aggregation) ------
  aggU_kernel<<<(NU + 31) / 32, TB, 0, stream>>>(hm8, rp_u, csr_u, aggb, NU);
  sage96u_kernel<<<(NU + 31) / 32, TB, 0, stream>>>(aggb, xub16, Wmu96, bl1_mu, u1, NU);
  zproj_kernel<<<(NU + 15) / 16, TB, 0, stream>>>(u1, Wl2_um, xu8);

  // ---- movie side: one gather pass serves features AND z ------------------
  agg24z_kernel<<<(NM + 31) / 32, TB, 0, stream>>>(xu8, rp_m, csr_m, a24, zagg, NM);
  sage_um_kernel<<<(NM + 31) / 32, TB, 0, stream>>>(a24, hm, Wum96, bl1_um, m1, NM);

  // ---- output ----
  out2_kernel<<<(NM + 3) / 4, TB, 0, stream>>>(zagg, m1, Wr2_um, bl2_um, outp, NM);
}